// Round 4
// baseline (379.369 us; speedup 1.0000x reference)
//
#include <hip/hip_runtime.h>
#include <math.h>

#define N_TOK 13824
#define KT 32
#define LOG2E 1.44269504088896f

typedef __attribute__((ext_vector_type(8)))  short bf16x8;
typedef __attribute__((ext_vector_type(4)))  float f32x4;
typedef __attribute__((ext_vector_type(16))) float f32x16;
typedef unsigned short u16;

#define AS3(p) ((__attribute__((address_space(3))) void*)(p))
#define AS1(p) ((const __attribute__((address_space(1))) void*)(p))
#define GLL(gp, lp) __builtin_amdgcn_global_load_lds(AS1(gp), AS3(lp), 16, 0, 0)

__device__ inline u16 f2b(float v) {
    union { float f; unsigned u; } a; a.f = v;
    unsigned r = a.u + 0x7fffu + ((a.u >> 16) & 1u);
    return (u16)(r >> 16);
}
__device__ inline float b2f(u16 v) {
    union { unsigned u; float f; } a; a.u = ((unsigned)v) << 16; return a.f;
}
__device__ inline float dev_exp2(float x) {       // 2^x via v_exp_f32 (+hazard nop)
    float r;
    asm volatile("v_exp_f32 %0, %1\n\ts_nop 0" : "=v"(r) : "v"(x));
    return r;
}
// v_permlane32_swap_b32 d, s : d.hi32 <-> s.lo32  (d'=[d.lo|s.lo], s'=[d.hi|s.hi])
__device__ inline float cross_max(float v) {
    float a = v, b = v;
    asm volatile("v_permlane32_swap_b32 %0, %1" : "+v"(a), "+v"(b));
    return fmaxf(a, b);
}
__device__ inline float cross_sum(float v) {
    float a = v, b = v;
    asm volatile("v_permlane32_swap_b32 %0, %1" : "+v"(a), "+v"(b));
    return a + b;
}
__device__ inline unsigned cvtpk(float lo, float hi) {
    unsigned r;
    asm volatile("v_cvt_pk_bf16_f32 %0, %1, %2" : "=v"(r) : "v"(lo), "v"(hi));
    return r;
}

// ---------------------------------------------------------------------------
// Kernel 0: x -> bf16; weights -> WcatT [320 n][256 k] bf16.
// g-columns (n in [256,288)) pre-scaled by log2e for log2-domain softmax.
// ---------------------------------------------------------------------------
__global__ __launch_bounds__(512) void prep_kernel(
    const float* __restrict__ x, const float* __restrict__ wh,
    const float* __restrict__ wg, const float* __restrict__ wf,
    u16* __restrict__ xb, u16* __restrict__ wt)
{
    int id = blockIdx.x * 512 + threadIdx.x;
    if (id < N_TOK * 256 / 4) {
        float4 v = ((const float4*)x)[id];
        ushort4 o;
        o.x = f2b(v.x); o.y = f2b(v.y); o.z = f2b(v.z); o.w = f2b(v.w);
        ((ushort4*)xb)[id] = o;
    }
    if (id < 320 * 256) {
        int n = id >> 8, k = id & 255;
        float v = (n < 256) ? wh[k * 256 + n]
                : (n < 288) ? wg[k * 32 + (n - 256)] * LOG2E
                            : wf[k * 32 + (n - 288)];
        wt[n * 256 + k] = f2b(v);
    }
}

// ---------------------------------------------------------------------------
// Kernel 1: proj GEMM  [13824,256] x [256,320] -> g[.,32] f[.,32] h[.,256]
// ---------------------------------------------------------------------------
__global__ __launch_bounds__(256) void proj_kernel(
    const u16* __restrict__ xb, const u16* __restrict__ wt,
    const float* __restrict__ bg, const float* __restrict__ bfv, const float* __restrict__ bh,
    u16* __restrict__ g, u16* __restrict__ f, u16* __restrict__ h)
{
    __shared__ u16 As[64 * 64];
    __shared__ u16 Bs[64 * 64];
    const int t = threadIdx.x, l = t & 63, w = t >> 6;
    const int m0 = blockIdx.x * 64, n0 = blockIdx.y * 64;
    const int mh = (w & 1) * 32, nh = (w >> 1) * 32;
    f32x4 acc[2][2] = {};

    for (int kstep = 0; kstep < 4; ++kstep) {
        const int k0 = kstep * 64;
        __syncthreads();
        #pragma unroll
        for (int i = 0; i < 2; ++i) {
            int ch  = w * 2 + i;
            int row = ch * 8 + (l >> 3);
            int ul  = (l & 7) ^ ((l >> 3) & 7);
            GLL(xb + (size_t)(m0 + row) * 256 + k0 + ul * 8, As + ch * 512);
            GLL(wt + (size_t)(n0 + row) * 256 + k0 + ul * 8, Bs + ch * 512);
        }
        asm volatile("s_waitcnt vmcnt(0)" ::: "memory");
        __syncthreads();
        #pragma unroll
        for (int ks = 0; ks < 2; ++ks) {
            bf16x8 a[2], b[2];
            #pragma unroll
            for (int mf = 0; mf < 2; ++mf) {
                int row = mh + mf * 16 + (l & 15);
                int u   = (ks * 4 + (l >> 4)) ^ (row & 7);
                a[mf] = *(const bf16x8*)(As + row * 64 + u * 8);
            }
            #pragma unroll
            for (int nf = 0; nf < 2; ++nf) {
                int row = nh + nf * 16 + (l & 15);
                int u   = (ks * 4 + (l >> 4)) ^ (row & 7);
                b[nf] = *(const bf16x8*)(Bs + row * 64 + u * 8);
            }
            #pragma unroll
            for (int mf = 0; mf < 2; ++mf)
                #pragma unroll
                for (int nf = 0; nf < 2; ++nf)
                    acc[mf][nf] = __builtin_amdgcn_mfma_f32_16x16x32_bf16(
                        a[mf], b[nf], acc[mf][nf], 0, 0, 0);
        }
    }

    #pragma unroll
    for (int mf = 0; mf < 2; ++mf)
        #pragma unroll
        for (int nf = 0; nf < 2; ++nf)
            #pragma unroll
            for (int r = 0; r < 4; ++r) {
                int row = m0 + mh + mf * 16 + (l >> 4) * 4 + r;
                int col = n0 + nh + nf * 16 + (l & 15);
                float bias = (col < 256) ? bh[col]
                           : (col < 288) ? bg[col - 256] * LOG2E
                                         : bfv[col - 288];
                u16 v = f2b(acc[mf][nf][r] + bias);
                if (col < 256)      h[(size_t)row * 256 + col] = v;
                else if (col < 288) g[(size_t)row * 32 + (col - 256)] = v;
                else                f[(size_t)row * 32 + (col - 288)] = v;
            }
}

// ---------------------------------------------------------------------------
// Kernel 2: transpose h [N,256] -> ht [256,N]
// ---------------------------------------------------------------------------
__global__ __launch_bounds__(256) void transpose_kernel(
    const u16* __restrict__ h, u16* __restrict__ ht)
{
    __shared__ u16 tile[64][65];
    const int t = threadIdx.x;
    const int r0 = blockIdx.x * 64, c0 = blockIdx.y * 64;
    #pragma unroll
    for (int i = 0; i < 16; ++i) {
        int r = i * 4 + (t >> 6), c = t & 63;
        tile[r][c] = h[(size_t)(r0 + r) * 256 + c0 + c];
    }
    __syncthreads();
    #pragma unroll
    for (int i = 0; i < 16; ++i) {
        int c = i * 4 + (t >> 6), r = t & 63;
        ht[(size_t)(c0 + c) * N_TOK + r0 + r] = tile[r][c];
    }
}

// ---------------------------------------------------------------------------
// Kernel 3: flash attention. QT=128/block, 4 waves (qg=w>>1, cg=w&1).
// KT=32. LDS units (16B) hold 8 keys of one row; physical unit index
// p = row*4 + (kg ^ ((row>>1)&3))  -> all 8 bank-groups per 8 rows.
// Scores in log2 domain (Q pre-scaled); softmax fully in-register.
// ---------------------------------------------------------------------------
__global__ __launch_bounds__(256) void attn_kernel(
    const u16* __restrict__ g, const u16* __restrict__ f, const u16* __restrict__ ht,
    u16* __restrict__ po, float* __restrict__ pm, float* __restrict__ pl,
    int kps, int ntiles)
{
    __shared__ u16 Vt[2][8192];        // 16KB each: 1024 units
    __shared__ u16 Ks[2][1024];        // 2KB each:  128 units
    __shared__ float rfs[4][2][32];

    const int t = threadIdx.x, l = t & 63, w = t >> 6;
    const int hi = l >> 5, l31 = l & 31;
    const int qg = w >> 1, cg = w & 1;
    const int q0 = blockIdx.x * 128;
    const int kbase = blockIdx.y * kps;

    // Q fragments: B[k][q], lane col q = l31, k = ks*16 + hi*8 + e
    bf16x8 qf[2][2];
    #pragma unroll
    for (int qs = 0; qs < 2; ++qs)
        #pragma unroll
        for (int ks = 0; ks < 2; ++ks)
            qf[qs][ks] = *(const bf16x8*)(g + (size_t)(q0 + qg * 64 + qs * 32 + l31) * 32
                                            + ks * 16 + hi * 8);

    f32x16 acc[2][4] = {};
    float m_run[2] = {-1e30f, -1e30f}, l_run[2] = {0.f, 0.f};

    // staging sources (per-lane, swizzled)
    const u16* vsrc[4];
    int vdst[4];
    #pragma unroll
    for (int i = 0; i < 4; ++i) {
        int u  = w * 256 + i * 64 + l;
        int ch = u >> 2, kg = (u & 3) ^ ((ch >> 1) & 3);
        vsrc[i] = ht + (size_t)ch * N_TOK + kbase + kg * 8;
        vdst[i] = u * 8;
    }
    const int ku = w * 64 + l;
    const int kkey = ku >> 2, kcb = (ku & 3) ^ ((kkey >> 1) & 3);
    const u16* ksrc = f + (size_t)(kbase + kkey) * 32 + kcb * 8;
    const int kdst = ku * 8;

    auto stage = [&](int tile, int buf) {
        const int koff = tile * KT;
        #pragma unroll
        for (int i = 0; i < 4; ++i)
            GLL(vsrc[i] + koff, Vt[buf] + vdst[i]);
        if (w < 2) GLL(ksrc + (size_t)koff * 32, Ks[buf] + kdst);
    };

    stage(0, 0);

    for (int tl = 0; tl < ntiles; ++tl) {
        const int buf = tl & 1;
        asm volatile("" ::: "memory");
        __builtin_amdgcn_s_barrier();                    // all done reading buf^1
        asm volatile("" ::: "memory");
        stage(tl + 1 < ntiles ? tl + 1 : 0, buf ^ 1);    // async prefetch
        if (w < 2) asm volatile("s_waitcnt vmcnt(5)" ::: "memory");
        else       asm volatile("s_waitcnt vmcnt(4)" ::: "memory");
        __builtin_amdgcn_s_barrier();                    // tile tl staged
        asm volatile("" ::: "memory");

        // K fragments: A[key][c], row key = l31, c = ks*16 + hi*8 + e
        bf16x8 kf[2];
        #pragma unroll
        for (int ks = 0; ks < 2; ++ks) {
            int kg = ks * 2 + hi;
            int un = l31 * 4 + (kg ^ ((l31 >> 1) & 3));
            kf[ks] = *(const bf16x8*)(Ks[buf] + un * 8);
        }

        // S = K Q^T : D[key][q], col q = l31, row key = (r&3)+8*(r>>2)+4*hi
        f32x16 s[2];
        #pragma unroll
        for (int qs = 0; qs < 2; ++qs) {
            f32x16 z = {};
            z = __builtin_amdgcn_mfma_f32_32x32x16_bf16(kf[0], qf[qs][0], z, 0, 0, 0);
            s[qs] = __builtin_amdgcn_mfma_f32_32x32x16_bf16(kf[1], qf[qs][1], z, 0, 0, 0);
        }

        // in-register online softmax (log2 domain) + P fragment build
        unsigned pa[2][2][4];
        #pragma unroll
        for (int qs = 0; qs < 2; ++qs) {
            // balanced max tree over 16 regs
            float m8[8];
            #pragma unroll
            for (int i = 0; i < 8; ++i) m8[i] = fmaxf(s[qs][i], s[qs][i + 8]);
            float m4a = fmaxf(m8[0], m8[1]), m4b = fmaxf(m8[2], m8[3]);
            float m4c = fmaxf(m8[4], m8[5]), m4d = fmaxf(m8[6], m8[7]);
            float mx = fmaxf(fmaxf(m4a, m4b), fmaxf(m4c, m4d));
            float mrow = cross_max(mx);
            if (!__all(mrow <= m_run[qs] + 11.54f)) {    // T13 defer-max (log2 units)
                float mnew = fmaxf(m_run[qs], mrow);
                float rf = dev_exp2(m_run[qs] - mnew);
                m_run[qs] = mnew;
                l_run[qs] *= rf;
                if (hi == 0) rfs[w][qs][l31] = rf;
                asm volatile("s_waitcnt lgkmcnt(0)" ::: "memory");
                __builtin_amdgcn_sched_barrier(0);
                float4 rv[4];
                #pragma unroll
                for (int b = 0; b < 4; ++b)
                    rv[b] = *(const float4*)&rfs[w][qs][b * 8 + hi * 4];
                #pragma unroll
                for (int cht = 0; cht < 4; ++cht)
                    #pragma unroll
                    for (int r = 0; r < 16; ++r)
                        acc[qs][cht][r] *= rv[r >> 2][r & 3];
            }
            float pv[16], sum;
            #pragma unroll
            for (int r = 0; r < 16; ++r) pv[r] = dev_exp2(s[qs][r] - m_run[qs]);
            {   // balanced sum tree
                float s8[8];
                #pragma unroll
                for (int i = 0; i < 8; ++i) s8[i] = pv[i] + pv[i + 8];
                float s4a = s8[0] + s8[1], s4b = s8[2] + s8[3];
                float s4c = s8[4] + s8[5], s4d = s8[6] + s8[7];
                sum = (s4a + s4b) + (s4c + s4d);
            }
            l_run[qs] += cross_sum(sum);
            // P -> A-fragment: swap(d=a0,s=a1): a0'=[a0.lo|a1.lo]=word0, a1'=word2
            #pragma unroll
            for (int ks = 0; ks < 2; ++ks) {
                const int o = ks * 8;
                unsigned a0 = cvtpk(pv[o + 0], pv[o + 1]);   // keys 4hi+{0,1}
                unsigned b0 = cvtpk(pv[o + 2], pv[o + 3]);   // keys 4hi+{2,3}
                unsigned a1 = cvtpk(pv[o + 4], pv[o + 5]);   // keys 8+4hi+{0,1}
                unsigned b1 = cvtpk(pv[o + 6], pv[o + 7]);   // keys 8+4hi+{2,3}
                asm volatile("v_permlane32_swap_b32 %0, %1" : "+v"(a0), "+v"(a1));
                asm volatile("v_permlane32_swap_b32 %0, %1" : "+v"(b0), "+v"(b1));
                pa[qs][ks][0] = a0; pa[qs][ks][1] = b0;      // words 0,1
                pa[qs][ks][2] = a1; pa[qs][ks][3] = b1;      // words 2,3
            }
        }

        // PV: A = P (regs), B = V^T (LDS b128, conflict-free swizzle)
        __builtin_amdgcn_s_setprio(1);
        #pragma unroll
        for (int ks = 0; ks < 2; ++ks) {
            const int kg = ks * 2 + hi;
            #pragma unroll
            for (int cht = 0; cht < 4; ++cht) {
                int ch = cg * 128 + cht * 32 + l31;
                int un = ch * 4 + (kg ^ ((ch >> 1) & 3));
                bf16x8 vf = *(const bf16x8*)(Vt[buf] + un * 8);
                #pragma unroll
                for (int qs = 0; qs < 2; ++qs) {
                    union { unsigned u[4]; bf16x8 v; } pb;
                    pb.u[0] = pa[qs][ks][0]; pb.u[1] = pa[qs][ks][1];
                    pb.u[2] = pa[qs][ks][2]; pb.u[3] = pa[qs][ks][3];
                    acc[qs][cht] = __builtin_amdgcn_mfma_f32_32x32x16_bf16(
                        pb.v, vf, acc[qs][cht], 0, 0, 0);
                }
            }
        }
        __builtin_amdgcn_s_setprio(0);
    }

    // epilogue: unnormalized partial O (bf16) + m,l
    const int split = blockIdx.y;
    #pragma unroll
    for (int qs = 0; qs < 2; ++qs) {
        #pragma unroll
        for (int cht = 0; cht < 4; ++cht) {
            int ch = cg * 128 + cht * 32 + l31;
            #pragma unroll
            for (int r = 0; r < 16; ++r) {
                int qq = q0 + qg * 64 + qs * 32 + (r & 3) + 8 * (r >> 2) + 4 * hi;
                po[((size_t)split * N_TOK + qq) * 256 + ch] = f2b(acc[qs][cht][r]);
            }
        }
        if (hi == 0 && cg == 0) {
            int qq = q0 + qg * 64 + qs * 32 + l31;
            pm[(size_t)split * N_TOK + qq] = m_run[qs];
            pl[(size_t)split * N_TOK + qq] = l_run[qs];
        }
    }
}

// ---------------------------------------------------------------------------
// Kernel 4: combine split partials; out = gamma*(O/l) + x
// ---------------------------------------------------------------------------
__global__ __launch_bounds__(256) void combine_kernel(
    const u16* __restrict__ po, const float* __restrict__ pm, const float* __restrict__ pl,
    const float* __restrict__ x, const float* __restrict__ gamma, float* __restrict__ out,
    int nsplit)
{
    const int t = threadIdx.x;
    const int q = blockIdx.x * 4 + (t >> 6);
    const int c4 = (t & 63) * 4;

    float M = -1e30f;
    for (int s = 0; s < nsplit; ++s) M = fmaxf(M, pm[(size_t)s * N_TOK + q]);
    float lsum = 0.f, o0 = 0.f, o1 = 0.f, o2 = 0.f, o3 = 0.f;
    for (int s = 0; s < nsplit; ++s) {
        float wsc = dev_exp2(pm[(size_t)s * N_TOK + q] - M);
        lsum += wsc * pl[(size_t)s * N_TOK + q];
        ushort4 p4 = *(const ushort4*)(po + ((size_t)s * N_TOK + q) * 256 + c4);
        o0 += wsc * b2f(p4.x); o1 += wsc * b2f(p4.y);
        o2 += wsc * b2f(p4.z); o3 += wsc * b2f(p4.w);
    }
    float inv = 1.f / lsum;
    float4 gm = *(const float4*)(gamma + c4);
    float4 xv = *(const float4*)(x + (size_t)q * 256 + c4);
    float4 ov;
    ov.x = gm.x * (o0 * inv) + xv.x;
    ov.y = gm.y * (o1 * inv) + xv.y;
    ov.z = gm.z * (o2 * inv) + xv.z;
    ov.w = gm.w * (o3 * inv) + xv.w;
    *(float4*)(out + (size_t)q * 256 + c4) = ov;
}

// ---------------------------------------------------------------------------
extern "C" void kernel_launch(void* const* d_in, const int* in_sizes, int n_in,
                              void* d_out, int out_size, void* d_ws, size_t ws_size,
                              hipStream_t stream) {
    const float* x     = (const float*)d_in[0];
    const float* wg    = (const float*)d_in[1];
    const float* bg    = (const float*)d_in[2];
    const float* wf    = (const float*)d_in[3];
    const float* bfv   = (const float*)d_in[4];
    const float* wh    = (const float*)d_in[5];
    const float* bh    = (const float*)d_in[6];
    const float* gamma = (const float*)d_in[7];
    float* out = (float*)d_out;

    // choose split count by available workspace
    const size_t base_b = (size_t)N_TOK * 32 * 2 * 2 + (size_t)N_TOK * 256 * 2; // gq+fk+ht
    auto need = [&](int ns) {
        return base_b + (size_t)ns * N_TOK * 256 * 2 + (size_t)ns * N_TOK * 8 + 1024;
    };
    int nsplit = 4;
    if (ws_size >= need(8)) nsplit = 8;
    else if (ws_size >= need(6)) nsplit = 6;
    const int kps = N_TOK / nsplit, ntiles = kps / KT;

    u16* ws = (u16*)d_ws;
    u16* gq = ws;                                   // N*32
    u16* fk = gq + (size_t)N_TOK * 32;              // N*32
    u16* ht = fk + (size_t)N_TOK * 32;              // N*256
    u16* po = ht + (size_t)N_TOK * 256;             // nsplit*N*256 (overlays scratch)
    u16* xb = po;                                   // scratch: N*256
    u16* wt = xb + (size_t)N_TOK * 256;             // 320*256
    u16* hv = wt + 320 * 256;                       // N*256
    float* pm = (float*)(po + (size_t)nsplit * N_TOK * 256);
    float* pl = pm + (size_t)nsplit * N_TOK;

    prep_kernel<<<1728, 512, 0, stream>>>(x, wh, wg, wf, xb, wt);
    proj_kernel<<<dim3(216, 5), 256, 0, stream>>>(xb, wt, bg, bfv, bh, gq, fk, hv);
    transpose_kernel<<<dim3(216, 4), 256, 0, stream>>>(hv, ht);
    attn_kernel<<<dim3(108, nsplit), 256, 0, stream>>>(gq, fk, ht, po, pm, pl, kps, ntiles);
    combine_kernel<<<N_TOK / 4, 256, 0, stream>>>(po, pm, pl, x, gamma, out, nsplit);
}

// Round 5
// 207.693 us; speedup vs baseline: 1.8266x; 1.8266x over previous
//
#include <hip/hip_runtime.h>
#include <math.h>

#define N_TOK 13824
#define KT 32
#define LOG2E 1.44269504088896f

typedef __attribute__((ext_vector_type(8)))  short bf16x8;
typedef __attribute__((ext_vector_type(4)))  float f32x4;
typedef __attribute__((ext_vector_type(16))) float f32x16;
typedef unsigned short u16;

#define AS3(p) ((__attribute__((address_space(3))) void*)(p))
#define AS1(p) ((const __attribute__((address_space(1))) void*)(p))
#define GLL(gp, lp) __builtin_amdgcn_global_load_lds(AS1(gp), AS3(lp), 16, 0, 0)

__device__ inline u16 f2b(float v) {
    union { float f; unsigned u; } a; a.f = v;
    unsigned r = a.u + 0x7fffu + ((a.u >> 16) & 1u);
    return (u16)(r >> 16);
}
__device__ inline float b2f(u16 v) {
    union { unsigned u; float f; } a; a.u = ((unsigned)v) << 16; return a.f;
}
__device__ inline float dev_exp2(float x) {       // 2^x via v_exp_f32 (+hazard nop)
    float r;
    asm volatile("v_exp_f32 %0, %1\n\ts_nop 0" : "=v"(r) : "v"(x));
    return r;
}
// v_permlane32_swap_b32 d, s : d.hi32 <-> s.lo32  (d'=[d.lo|s.lo], s'=[d.hi|s.hi])
__device__ inline float cross_max(float v) {
    float a = v, b = v;
    asm volatile("v_permlane32_swap_b32 %0, %1" : "+v"(a), "+v"(b));
    return fmaxf(a, b);
}
__device__ inline float cross_sum(float v) {
    float a = v, b = v;
    asm volatile("v_permlane32_swap_b32 %0, %1" : "+v"(a), "+v"(b));
    return a + b;
}
__device__ inline unsigned cvtpk(float lo, float hi) {
    unsigned r;
    asm volatile("v_cvt_pk_bf16_f32 %0, %1, %2" : "=v"(r) : "v"(lo), "v"(hi));
    return r;
}

// ---------------------------------------------------------------------------
// Kernel 0: x -> bf16; weights -> WcatT [320 n][256 k] bf16.
// g-columns (n in [256,288)) pre-scaled by log2e for log2-domain softmax.
// ---------------------------------------------------------------------------
__global__ __launch_bounds__(512) void prep_kernel(
    const float* __restrict__ x, const float* __restrict__ wh,
    const float* __restrict__ wg, const float* __restrict__ wf,
    u16* __restrict__ xb, u16* __restrict__ wt)
{
    int id = blockIdx.x * 512 + threadIdx.x;
    if (id < N_TOK * 256 / 4) {
        float4 v = ((const float4*)x)[id];
        ushort4 o;
        o.x = f2b(v.x); o.y = f2b(v.y); o.z = f2b(v.z); o.w = f2b(v.w);
        ((ushort4*)xb)[id] = o;
    }
    if (id < 320 * 256) {
        int n = id >> 8, k = id & 255;
        float v = (n < 256) ? wh[k * 256 + n]
                : (n < 288) ? wg[k * 32 + (n - 256)] * LOG2E
                            : wf[k * 32 + (n - 288)];
        wt[n * 256 + k] = f2b(v);
    }
}

// ---------------------------------------------------------------------------
// Kernel 1: proj GEMM  [13824,256] x [256,320] -> g[.,32] f[.,32] h[.,256]
// ---------------------------------------------------------------------------
__global__ __launch_bounds__(256) void proj_kernel(
    const u16* __restrict__ xb, const u16* __restrict__ wt,
    const float* __restrict__ bg, const float* __restrict__ bfv, const float* __restrict__ bh,
    u16* __restrict__ g, u16* __restrict__ f, u16* __restrict__ h)
{
    __shared__ u16 As[64 * 64];
    __shared__ u16 Bs[64 * 64];
    const int t = threadIdx.x, l = t & 63, w = t >> 6;
    const int m0 = blockIdx.x * 64, n0 = blockIdx.y * 64;
    const int mh = (w & 1) * 32, nh = (w >> 1) * 32;
    f32x4 acc[2][2] = {};

    for (int kstep = 0; kstep < 4; ++kstep) {
        const int k0 = kstep * 64;
        __syncthreads();
        #pragma unroll
        for (int i = 0; i < 2; ++i) {
            int ch  = w * 2 + i;
            int row = ch * 8 + (l >> 3);
            int ul  = (l & 7) ^ ((l >> 3) & 7);
            GLL(xb + (size_t)(m0 + row) * 256 + k0 + ul * 8, As + ch * 512);
            GLL(wt + (size_t)(n0 + row) * 256 + k0 + ul * 8, Bs + ch * 512);
        }
        asm volatile("s_waitcnt vmcnt(0)" ::: "memory");
        __syncthreads();
        #pragma unroll
        for (int ks = 0; ks < 2; ++ks) {
            bf16x8 a[2], b[2];
            #pragma unroll
            for (int mf = 0; mf < 2; ++mf) {
                int row = mh + mf * 16 + (l & 15);
                int u   = (ks * 4 + (l >> 4)) ^ (row & 7);
                a[mf] = *(const bf16x8*)(As + row * 64 + u * 8);
            }
            #pragma unroll
            for (int nf = 0; nf < 2; ++nf) {
                int row = nh + nf * 16 + (l & 15);
                int u   = (ks * 4 + (l >> 4)) ^ (row & 7);
                b[nf] = *(const bf16x8*)(Bs + row * 64 + u * 8);
            }
            #pragma unroll
            for (int mf = 0; mf < 2; ++mf)
                #pragma unroll
                for (int nf = 0; nf < 2; ++nf)
                    acc[mf][nf] = __builtin_amdgcn_mfma_f32_16x16x32_bf16(
                        a[mf], b[nf], acc[mf][nf], 0, 0, 0);
        }
    }

    #pragma unroll
    for (int mf = 0; mf < 2; ++mf)
        #pragma unroll
        for (int nf = 0; nf < 2; ++nf)
            #pragma unroll
            for (int r = 0; r < 4; ++r) {
                int row = m0 + mh + mf * 16 + (l >> 4) * 4 + r;
                int col = n0 + nh + nf * 16 + (l & 15);
                float bias = (col < 256) ? bh[col]
                           : (col < 288) ? bg[col - 256] * LOG2E
                                         : bfv[col - 288];
                u16 v = f2b(acc[mf][nf][r] + bias);
                if (col < 256)      h[(size_t)row * 256 + col] = v;
                else if (col < 288) g[(size_t)row * 32 + (col - 256)] = v;
                else                f[(size_t)row * 32 + (col - 288)] = v;
            }
}

// ---------------------------------------------------------------------------
// Kernel 2: transpose h [N,256] -> ht [256,N]
// ---------------------------------------------------------------------------
__global__ __launch_bounds__(256) void transpose_kernel(
    const u16* __restrict__ h, u16* __restrict__ ht)
{
    __shared__ u16 tile[64][65];
    const int t = threadIdx.x;
    const int r0 = blockIdx.x * 64, c0 = blockIdx.y * 64;
    #pragma unroll
    for (int i = 0; i < 16; ++i) {
        int r = i * 4 + (t >> 6), c = t & 63;
        tile[r][c] = h[(size_t)(r0 + r) * 256 + c0 + c];
    }
    __syncthreads();
    #pragma unroll
    for (int i = 0; i < 16; ++i) {
        int c = i * 4 + (t >> 6), r = t & 63;
        ht[(size_t)(c0 + c) * N_TOK + r0 + r] = tile[r][c];
    }
}

// ---------------------------------------------------------------------------
// Kernel 3: flash attention. QT=128/block, 4 waves (qg=w>>1, cg=w&1).
// __launch_bounds__(256,2): cap 256 unified regs/wave -> 2 blocks/CU.
// KT=32. 16B LDS units; physical unit p = row*4 + (kg ^ ((row>>1)&3)).
// log2-domain scores; in-register online softmax; split-K partials.
// ---------------------------------------------------------------------------
__global__ __launch_bounds__(256, 2) void attn_kernel(
    const u16* __restrict__ g, const u16* __restrict__ f, const u16* __restrict__ ht,
    u16* __restrict__ po, float* __restrict__ pm, float* __restrict__ pl,
    int kps, int ntiles)
{
    __shared__ u16 Vt[2][8192];        // 16KB each: 1024 units
    __shared__ u16 Ks[2][1024];        // 2KB each:  128 units
    __shared__ float rfs[4][2][32];

    const int t = threadIdx.x, l = t & 63, w = t >> 6;
    const int hi = l >> 5, l31 = l & 31;
    const int qg = w >> 1, cg = w & 1;
    const int q0 = blockIdx.x * 128;
    const int kbase = blockIdx.y * kps;

    // Q fragments: B[k][q], lane col q = l31, k = ks*16 + hi*8 + e
    bf16x8 qf[2][2];
    #pragma unroll
    for (int qs = 0; qs < 2; ++qs)
        #pragma unroll
        for (int ks = 0; ks < 2; ++ks)
            qf[qs][ks] = *(const bf16x8*)(g + (size_t)(q0 + qg * 64 + qs * 32 + l31) * 32
                                            + ks * 16 + hi * 8);

    f32x16 acc[2][4] = {};
    float m_run[2] = {-1e30f, -1e30f}, l_run[2] = {0.f, 0.f};

    // per-lane staging offsets (32-bit, element units) + uniform bases
    const u16* vbase = ht + kbase;
    int voff[4];
    #pragma unroll
    for (int i = 0; i < 4; ++i) {
        int u  = w * 256 + i * 64 + l;
        int ch = u >> 2, kg = (u & 3) ^ ((ch >> 1) & 3);
        voff[i] = ch * N_TOK + kg * 8;
    }
    const u16* kbase_p = f + (size_t)kbase * 32;
    const int ku = w * 64 + l;
    const int kkey = ku >> 2, kcb = (ku & 3) ^ ((kkey >> 1) & 3);
    const int koffK = kkey * 32 + kcb * 8;

    auto stage = [&](int tile, int buf) {
        const int ke = tile * KT;                  // key offset within split
        const u16* vb = vbase + ke;
        #pragma unroll
        for (int i = 0; i < 4; ++i)
            GLL(vb + voff[i], Vt[buf] + (w * 256 + i * 64 + l) * 8);
        if (w < 2) GLL(kbase_p + ke * 32 + koffK, Ks[buf] + ku * 8);
    };

    stage(0, 0);

    for (int tl = 0; tl < ntiles; ++tl) {
        const int buf = tl & 1;
        asm volatile("" ::: "memory");
        __builtin_amdgcn_s_barrier();                    // all done reading buf^1
        asm volatile("" ::: "memory");
        stage(tl + 1 < ntiles ? tl + 1 : 0, buf ^ 1);    // async prefetch
        if (w < 2) asm volatile("s_waitcnt vmcnt(5)" ::: "memory");
        else       asm volatile("s_waitcnt vmcnt(4)" ::: "memory");
        __builtin_amdgcn_s_barrier();                    // tile tl staged
        asm volatile("" ::: "memory");

        // K fragments: A[key][c], row key = l31, c = ks*16 + hi*8 + e
        bf16x8 kf[2];
        #pragma unroll
        for (int ks = 0; ks < 2; ++ks) {
            int kg = ks * 2 + hi;
            int un = l31 * 4 + (kg ^ ((l31 >> 1) & 3));
            kf[ks] = *(const bf16x8*)(Ks[buf] + un * 8);
        }

        // per-qs: S = K Q^T, online softmax (log2), P fragment build
        unsigned pa[2][2][4];
        #pragma unroll
        for (int qs = 0; qs < 2; ++qs) {
            f32x16 z = {};
            z = __builtin_amdgcn_mfma_f32_32x32x16_bf16(kf[0], qf[qs][0], z, 0, 0, 0);
            f32x16 s = __builtin_amdgcn_mfma_f32_32x32x16_bf16(kf[1], qf[qs][1], z, 0, 0, 0);

            float m8[8];
            #pragma unroll
            for (int i = 0; i < 8; ++i) m8[i] = fmaxf(s[i], s[i + 8]);
            float m4a = fmaxf(m8[0], m8[1]), m4b = fmaxf(m8[2], m8[3]);
            float m4c = fmaxf(m8[4], m8[5]), m4d = fmaxf(m8[6], m8[7]);
            float mx = fmaxf(fmaxf(m4a, m4b), fmaxf(m4c, m4d));
            float mrow = cross_max(mx);
            if (!__all(mrow <= m_run[qs] + 11.54f)) {    // defer-max (log2 units)
                float mnew = fmaxf(m_run[qs], mrow);
                float rf = dev_exp2(m_run[qs] - mnew);
                m_run[qs] = mnew;
                l_run[qs] *= rf;
                if (hi == 0) rfs[w][qs][l31] = rf;
                asm volatile("s_waitcnt lgkmcnt(0)" ::: "memory");
                __builtin_amdgcn_sched_barrier(0);
                float4 rv[4];
                #pragma unroll
                for (int b = 0; b < 4; ++b)
                    rv[b] = *(const float4*)&rfs[w][qs][b * 8 + hi * 4];
                #pragma unroll
                for (int cht = 0; cht < 4; ++cht)
                    #pragma unroll
                    for (int r = 0; r < 16; ++r)
                        acc[qs][cht][r] *= rv[r >> 2][r & 3];
            }
            float pv[16];
            #pragma unroll
            for (int r = 0; r < 16; ++r) pv[r] = dev_exp2(s[r] - m_run[qs]);
            float s8[8];
            #pragma unroll
            for (int i = 0; i < 8; ++i) s8[i] = pv[i] + pv[i + 8];
            float s4a = s8[0] + s8[1], s4b = s8[2] + s8[3];
            float s4c = s8[4] + s8[5], s4d = s8[6] + s8[7];
            l_run[qs] += cross_sum((s4a + s4b) + (s4c + s4d));
            // P -> A-fragment: swap(d=a0,s=a1): a0'=[a0.lo|a1.lo]=word0, a1'=word2
            #pragma unroll
            for (int ks = 0; ks < 2; ++ks) {
                const int o = ks * 8;
                unsigned a0 = cvtpk(pv[o + 0], pv[o + 1]);   // keys 4hi+{0,1}
                unsigned b0 = cvtpk(pv[o + 2], pv[o + 3]);   // keys 4hi+{2,3}
                unsigned a1 = cvtpk(pv[o + 4], pv[o + 5]);   // keys 8+4hi+{0,1}
                unsigned b1 = cvtpk(pv[o + 6], pv[o + 7]);   // keys 8+4hi+{2,3}
                asm volatile("v_permlane32_swap_b32 %0, %1" : "+v"(a0), "+v"(a1));
                asm volatile("v_permlane32_swap_b32 %0, %1" : "+v"(b0), "+v"(b1));
                pa[qs][ks][0] = a0; pa[qs][ks][1] = b0;      // words 0,1
                pa[qs][ks][2] = a1; pa[qs][ks][3] = b1;      // words 2,3
            }
        }

        // PV: A = P (regs), B = V^T (LDS b128, conflict-free swizzle)
        __builtin_amdgcn_s_setprio(1);
        #pragma unroll
        for (int ks = 0; ks < 2; ++ks) {
            const int kg = ks * 2 + hi;
            #pragma unroll
            for (int cht = 0; cht < 4; ++cht) {
                int ch = cg * 128 + cht * 32 + l31;
                int un = ch * 4 + (kg ^ ((ch >> 1) & 3));
                bf16x8 vf = *(const bf16x8*)(Vt[buf] + un * 8);
                #pragma unroll
                for (int qs = 0; qs < 2; ++qs) {
                    union { unsigned u[4]; bf16x8 v; } pb;
                    pb.u[0] = pa[qs][ks][0]; pb.u[1] = pa[qs][ks][1];
                    pb.u[2] = pa[qs][ks][2]; pb.u[3] = pa[qs][ks][3];
                    acc[qs][cht] = __builtin_amdgcn_mfma_f32_32x32x16_bf16(
                        pb.v, vf, acc[qs][cht], 0, 0, 0);
                }
            }
        }
        __builtin_amdgcn_s_setprio(0);
    }

    // epilogue: unnormalized partial O (bf16) + m,l
    const int split = blockIdx.y;
    #pragma unroll
    for (int qs = 0; qs < 2; ++qs) {
        #pragma unroll
        for (int cht = 0; cht < 4; ++cht) {
            int ch = cg * 128 + cht * 32 + l31;
            #pragma unroll
            for (int r = 0; r < 16; ++r) {
                int qq = q0 + qg * 64 + qs * 32 + (r & 3) + 8 * (r >> 2) + 4 * hi;
                po[((size_t)split * N_TOK + qq) * 256 + ch] = f2b(acc[qs][cht][r]);
            }
        }
        if (hi == 0 && cg == 0) {
            int qq = q0 + qg * 64 + qs * 32 + l31;
            pm[(size_t)split * N_TOK + qq] = m_run[qs];
            pl[(size_t)split * N_TOK + qq] = l_run[qs];
        }
    }
}

// ---------------------------------------------------------------------------
// Kernel 4: combine split partials; out = gamma*(O/l) + x
// ---------------------------------------------------------------------------
__global__ __launch_bounds__(256) void combine_kernel(
    const u16* __restrict__ po, const float* __restrict__ pm, const float* __restrict__ pl,
    const float* __restrict__ x, const float* __restrict__ gamma, float* __restrict__ out,
    int nsplit)
{
    const int t = threadIdx.x;
    const int q = blockIdx.x * 4 + (t >> 6);
    const int c4 = (t & 63) * 4;

    float M = -1e30f;
    for (int s = 0; s < nsplit; ++s) M = fmaxf(M, pm[(size_t)s * N_TOK + q]);
    float lsum = 0.f, o0 = 0.f, o1 = 0.f, o2 = 0.f, o3 = 0.f;
    for (int s = 0; s < nsplit; ++s) {
        float wsc = dev_exp2(pm[(size_t)s * N_TOK + q] - M);
        lsum += wsc * pl[(size_t)s * N_TOK + q];
        ushort4 p4 = *(const ushort4*)(po + ((size_t)s * N_TOK + q) * 256 + c4);
        o0 += wsc * b2f(p4.x); o1 += wsc * b2f(p4.y);
        o2 += wsc * b2f(p4.z); o3 += wsc * b2f(p4.w);
    }
    float inv = 1.f / lsum;
    float4 gm = *(const float4*)(gamma + c4);
    float4 xv = *(const float4*)(x + (size_t)q * 256 + c4);
    float4 ov;
    ov.x = gm.x * (o0 * inv) + xv.x;
    ov.y = gm.y * (o1 * inv) + xv.y;
    ov.z = gm.z * (o2 * inv) + xv.z;
    ov.w = gm.w * (o3 * inv) + xv.w;
    *(float4*)(out + (size_t)q * 256 + c4) = ov;
}

// ---------------------------------------------------------------------------
extern "C" void kernel_launch(void* const* d_in, const int* in_sizes, int n_in,
                              void* d_out, int out_size, void* d_ws, size_t ws_size,
                              hipStream_t stream) {
    const float* x     = (const float*)d_in[0];
    const float* wg    = (const float*)d_in[1];
    const float* bg    = (const float*)d_in[2];
    const float* wf    = (const float*)d_in[3];
    const float* bfv   = (const float*)d_in[4];
    const float* wh    = (const float*)d_in[5];
    const float* bh    = (const float*)d_in[6];
    const float* gamma = (const float*)d_in[7];
    float* out = (float*)d_out;

    // choose split count by available workspace (blocks = 108 * nsplit)
    const size_t base_b = (size_t)N_TOK * 640;          // gq + fk + ht bytes
    auto need = [&](int ns) {
        return base_b + (size_t)ns * N_TOK * 512 + (size_t)ns * N_TOK * 8 + 1024;
    };
    int nsplit = 4;
    if (ws_size >= need(9)) nsplit = 9;
    else if (ws_size >= need(8)) nsplit = 8;
    else if (ws_size >= need(6)) nsplit = 6;
    const int kps = N_TOK / nsplit, ntiles = kps / KT;

    u16* ws = (u16*)d_ws;
    u16* gq = ws;                                   // N*32
    u16* fk = gq + (size_t)N_TOK * 32;              // N*32
    u16* ht = fk + (size_t)N_TOK * 32;              // N*256
    u16* po = ht + (size_t)N_TOK * 256;             // nsplit*N*256 (overlays scratch)
    u16* xb = po;                                   // scratch: N*256
    u16* wt = xb + (size_t)N_TOK * 256;             // 320*256
    u16* hv = wt + 320 * 256;                       // N*256
    float* pm = (float*)(po + (size_t)nsplit * N_TOK * 256);
    float* pl = pm + (size_t)nsplit * N_TOK;

    prep_kernel<<<1728, 512, 0, stream>>>(x, wh, wg, wf, xb, wt);
    proj_kernel<<<dim3(216, 5), 256, 0, stream>>>(xb, wt, bg, bfv, bh, gq, fk, hv);
    transpose_kernel<<<dim3(216, 4), 256, 0, stream>>>(hv, ht);
    attn_kernel<<<dim3(108, nsplit), 256, 0, stream>>>(gq, fk, ht, po, pm, pl, kps, ntiles);
    combine_kernel<<<N_TOK / 4, 256, 0, stream>>>(po, pm, pl, x, gamma, out, nsplit);
}

// Round 6
// 194.570 us; speedup vs baseline: 1.9498x; 1.0674x over previous
//
#include <hip/hip_runtime.h>
#include <math.h>

#define N_TOK 13824
#define KT 64
#define LOG2E 1.44269504088896f

typedef __attribute__((ext_vector_type(8)))  short bf16x8;
typedef __attribute__((ext_vector_type(4)))  float f32x4;
typedef __attribute__((ext_vector_type(16))) float f32x16;
typedef unsigned short u16;

#define AS3(p) ((__attribute__((address_space(3))) void*)(p))
#define AS1(p) ((const __attribute__((address_space(1))) void*)(p))
#define GLL(gp, lp) __builtin_amdgcn_global_load_lds(AS1(gp), AS3(lp), 16, 0, 0)

__device__ inline u16 f2b(float v) {
    union { float f; unsigned u; } a; a.f = v;
    unsigned r = a.u + 0x7fffu + ((a.u >> 16) & 1u);
    return (u16)(r >> 16);
}
__device__ inline float b2f(u16 v) {
    union { unsigned u; float f; } a; a.u = ((unsigned)v) << 16; return a.f;
}
__device__ inline float dev_exp2(float x) {       // 2^x via v_exp_f32 (no hazard nop on CDNA)
    float r;
    asm volatile("v_exp_f32 %0, %1" : "=v"(r) : "v"(x));
    return r;
}
// v_permlane32_swap_b32 d, s : lanes<32 of result-d keep d, lanes>=32 get s's low lanes, etc.
__device__ inline float cross_max(float v) {
    float a = v, b = v;
    asm volatile("v_permlane32_swap_b32 %0, %1" : "+v"(a), "+v"(b));
    return fmaxf(a, b);
}
__device__ inline float cross_sum(float v) {
    float a = v, b = v;
    asm volatile("v_permlane32_swap_b32 %0, %1" : "+v"(a), "+v"(b));
    return a + b;
}
__device__ inline unsigned cvtpk(float lo, float hi) {
    unsigned r;
    asm volatile("v_cvt_pk_bf16_f32 %0, %1, %2" : "=v"(r) : "v"(lo), "v"(hi));
    return r;
}

// ---------------------------------------------------------------------------
// Kernel 0: x -> bf16; weights -> WcatT [320 n][256 k] bf16.
// g-columns (n in [256,288)) pre-scaled by log2e for log2-domain softmax.
// ---------------------------------------------------------------------------
__global__ __launch_bounds__(512) void prep_kernel(
    const float* __restrict__ x, const float* __restrict__ wh,
    const float* __restrict__ wg, const float* __restrict__ wf,
    u16* __restrict__ xb, u16* __restrict__ wt)
{
    int id = blockIdx.x * 512 + threadIdx.x;
    if (id < N_TOK * 256 / 4) {
        float4 v = ((const float4*)x)[id];
        ushort4 o;
        o.x = f2b(v.x); o.y = f2b(v.y); o.z = f2b(v.z); o.w = f2b(v.w);
        ((ushort4*)xb)[id] = o;
    }
    if (id < 320 * 256) {
        int n = id >> 8, k = id & 255;
        float v = (n < 256) ? wh[k * 256 + n]
                : (n < 288) ? wg[k * 32 + (n - 256)] * LOG2E
                            : wf[k * 32 + (n - 288)];
        wt[n * 256 + k] = f2b(v);
    }
}

// ---------------------------------------------------------------------------
// Kernel 1: proj GEMM  [13824,256] x [256,320] -> g[.,32] f[.,32] h[.,256]
// ---------------------------------------------------------------------------
__global__ __launch_bounds__(256) void proj_kernel(
    const u16* __restrict__ xb, const u16* __restrict__ wt,
    const float* __restrict__ bg, const float* __restrict__ bfv, const float* __restrict__ bh,
    u16* __restrict__ g, u16* __restrict__ f, u16* __restrict__ h)
{
    __shared__ u16 As[64 * 64];
    __shared__ u16 Bs[64 * 64];
    const int t = threadIdx.x, l = t & 63, w = t >> 6;
    const int m0 = blockIdx.x * 64, n0 = blockIdx.y * 64;
    const int mh = (w & 1) * 32, nh = (w >> 1) * 32;
    f32x4 acc[2][2] = {};

    for (int kstep = 0; kstep < 4; ++kstep) {
        const int k0 = kstep * 64;
        __syncthreads();
        #pragma unroll
        for (int i = 0; i < 2; ++i) {
            int ch  = w * 2 + i;
            int row = ch * 8 + (l >> 3);
            int ul  = (l & 7) ^ ((l >> 3) & 7);
            GLL(xb + (size_t)(m0 + row) * 256 + k0 + ul * 8, As + ch * 512);
            GLL(wt + (size_t)(n0 + row) * 256 + k0 + ul * 8, Bs + ch * 512);
        }
        asm volatile("s_waitcnt vmcnt(0)" ::: "memory");
        __syncthreads();
        #pragma unroll
        for (int ks = 0; ks < 2; ++ks) {
            bf16x8 a[2], b[2];
            #pragma unroll
            for (int mf = 0; mf < 2; ++mf) {
                int row = mh + mf * 16 + (l & 15);
                int u   = (ks * 4 + (l >> 4)) ^ (row & 7);
                a[mf] = *(const bf16x8*)(As + row * 64 + u * 8);
            }
            #pragma unroll
            for (int nf = 0; nf < 2; ++nf) {
                int row = nh + nf * 16 + (l & 15);
                int u   = (ks * 4 + (l >> 4)) ^ (row & 7);
                b[nf] = *(const bf16x8*)(Bs + row * 64 + u * 8);
            }
            #pragma unroll
            for (int mf = 0; mf < 2; ++mf)
                #pragma unroll
                for (int nf = 0; nf < 2; ++nf)
                    acc[mf][nf] = __builtin_amdgcn_mfma_f32_16x16x32_bf16(
                        a[mf], b[nf], acc[mf][nf], 0, 0, 0);
        }
    }

    #pragma unroll
    for (int mf = 0; mf < 2; ++mf)
        #pragma unroll
        for (int nf = 0; nf < 2; ++nf)
            #pragma unroll
            for (int r = 0; r < 4; ++r) {
                int row = m0 + mh + mf * 16 + (l >> 4) * 4 + r;
                int col = n0 + nh + nf * 16 + (l & 15);
                float bias = (col < 256) ? bh[col]
                           : (col < 288) ? bg[col - 256] * LOG2E
                                         : bfv[col - 288];
                u16 v = f2b(acc[mf][nf][r] + bias);
                if (col < 256)      h[(size_t)row * 256 + col] = v;
                else if (col < 288) g[(size_t)row * 32 + (col - 256)] = v;
                else                f[(size_t)row * 32 + (col - 288)] = v;
            }
}

// ---------------------------------------------------------------------------
// Kernel 2: transpose h [N,256] -> ht [256,N]
// ---------------------------------------------------------------------------
__global__ __launch_bounds__(256) void transpose_kernel(
    const u16* __restrict__ h, u16* __restrict__ ht)
{
    __shared__ u16 tile[64][65];
    const int t = threadIdx.x;
    const int r0 = blockIdx.x * 64, c0 = blockIdx.y * 64;
    #pragma unroll
    for (int i = 0; i < 16; ++i) {
        int r = i * 4 + (t >> 6), c = t & 63;
        tile[r][c] = h[(size_t)(r0 + r) * 256 + c0 + c];
    }
    __syncthreads();
    #pragma unroll
    for (int i = 0; i < 16; ++i) {
        int c = i * 4 + (t >> 6), r = t & 63;
        ht[(size_t)(c0 + c) * N_TOK + r0 + r] = tile[r][c];
    }
}

// ---------------------------------------------------------------------------
// Kernel 3: flash attention. QT=128/block, 4 waves (qg=w>>1, cg=w&1).
// KT=64 staged per barrier pair, computed as 2x 32-key sub-phases.
// 2x-unrolled tile loop: buf compile-time; all LDS indices precomputed
// with XOR bank-swizzle folded in; reads use immediate offsets.
// ---------------------------------------------------------------------------
__global__ __launch_bounds__(256, 2) void attn_kernel(
    const u16* __restrict__ g, const u16* __restrict__ f, const u16* __restrict__ ht,
    u16* __restrict__ po, float* __restrict__ pm, float* __restrict__ pl,
    int kps, int ntiles)
{
    __shared__ u16 VtF[2 * 16384];     // 2 x 32KB V^T tile: unit(ch,kg): p=ch*8+(kg^(ch&7))
    __shared__ u16 KsF[2 * 2048];      // 2 x 4KB  K tile:   unit(key,cu): p=key*4+(cu^(key&3))
    __shared__ float rfs[4][2][32];

    const int t = threadIdx.x, l = t & 63, w = t >> 6;
    const int hi = l >> 5, l31 = l & 31;
    const int qg = w >> 1, cg = w & 1;
    const int q0 = blockIdx.x * 128;
    const int kbase = blockIdx.y * kps;

    // Q fragments: B[k][q], lane col q = l31, k = ks*16 + hi*8 + e
    bf16x8 qf[2][2];
    #pragma unroll
    for (int qs = 0; qs < 2; ++qs)
        #pragma unroll
        for (int ks = 0; ks < 2; ++ks)
            qf[qs][ks] = *(const bf16x8*)(g + (size_t)(q0 + qg * 64 + qs * 32 + l31) * 32
                                            + ks * 16 + hi * 8);

    f32x16 acc[2][4] = {};
    float m_run[2] = {-1e30f, -1e30f}, l_run[2] = {0.f, 0.f};

    // ---- staging offsets (per-lane, element units) ----
    int voffV[8];
    #pragma unroll
    for (int i = 0; i < 8; ++i) {
        int p = i * 256 + t;
        int ch = p >> 3, kg = (p & 7) ^ (ch & 7);
        voffV[i] = ch * N_TOK + kg * 8;
    }
    int koffK;
    { int key = t >> 2, cu = (t & 3) ^ (key & 3); koffK = key * 32 + cu * 8; }

    // ---- compute-read indices (swizzle folded; buf folded) ----
    const int swv = l31 & 7, swk = l31 & 3;
    const int baseV = (cg * 128 + l31) * 64 + ((hi ^ swv) & 7) * 8;
    const int baseK = l31 * 32 + ((hi ^ swk) & 3) * 8;
    int iV[2][4], iK[2][2];
    #pragma unroll
    for (int b = 0; b < 2; ++b) {
        #pragma unroll
        for (int ksl = 0; ksl < 4; ++ksl) iV[b][ksl] = b * 16384 + (baseV ^ (ksl << 4));
        #pragma unroll
        for (int ks = 0; ks < 2; ++ks)    iK[b][ks]  = b * 2048  + (baseK ^ (ks << 4));
    }

    auto stage = [&](int tile, int db) {
        const u16* vsrc = ht + kbase + tile * KT;
        #pragma unroll
        for (int i = 0; i < 8; ++i)
            GLL(vsrc + voffV[i], &VtF[db * 16384 + (i * 256 + t) * 8]);
        GLL(f + (size_t)(kbase + tile * KT) * 32 + koffK, &KsF[db * 2048 + t * 8]);
    };

    stage(0, 0);

    for (int tl = 0; tl < ntiles; tl += 2) {
        #pragma unroll
        for (int sub = 0; sub < 2; ++sub) {
            const int b = sub, cur = tl + sub;
            asm volatile("" ::: "memory");
            __builtin_amdgcn_s_barrier();            // all done reading buf b^1
            asm volatile("" ::: "memory");
            { int nx = cur + 1 < ntiles ? cur + 1 : 0; stage(nx, b ^ 1); }
            asm volatile("s_waitcnt vmcnt(9)" ::: "memory");
            __builtin_amdgcn_s_barrier();            // tile cur staged
            asm volatile("" ::: "memory");

            #pragma unroll
            for (int kb = 0; kb < 2; ++kb) {
                // K fragments: A[key][c], row key = kb*32+l31
                bf16x8 kf0 = *(const bf16x8*)&KsF[iK[b][0] + kb * 1024];
                bf16x8 kf1 = *(const bf16x8*)&KsF[iK[b][1] + kb * 1024];

                unsigned pa[2][2][4];
                #pragma unroll
                for (int qs = 0; qs < 2; ++qs) {
                    f32x16 z = {};
                    z = __builtin_amdgcn_mfma_f32_32x32x16_bf16(kf0, qf[qs][0], z, 0, 0, 0);
                    f32x16 s = __builtin_amdgcn_mfma_f32_32x32x16_bf16(kf1, qf[qs][1], z, 0, 0, 0);

                    // max over 16 regs via v_max3 triples
                    float m1 = fmaxf(fmaxf(s[0], s[1]), s[2]);
                    float m2 = fmaxf(fmaxf(s[3], s[4]), s[5]);
                    float m3 = fmaxf(fmaxf(s[6], s[7]), s[8]);
                    float m4 = fmaxf(fmaxf(s[9], s[10]), s[11]);
                    float m5 = fmaxf(fmaxf(s[12], s[13]), s[14]);
                    float mA = fmaxf(fmaxf(m1, m2), m3);
                    float mB = fmaxf(fmaxf(m4, m5), s[15]);
                    float mrow = cross_max(fmaxf(mA, mB));

                    if (!__all(mrow <= m_run[qs] + 11.54f)) {   // defer-max (log2 units)
                        float mnew = fmaxf(m_run[qs], mrow);
                        float rf = dev_exp2(m_run[qs] - mnew);
                        m_run[qs] = mnew;
                        l_run[qs] *= rf;
                        if (hi == 0) rfs[w][qs][l31] = rf;
                        asm volatile("s_waitcnt lgkmcnt(0)" ::: "memory");
                        __builtin_amdgcn_sched_barrier(0);
                        float4 rv[4];
                        #pragma unroll
                        for (int bb = 0; bb < 4; ++bb)
                            rv[bb] = *(const float4*)&rfs[w][qs][bb * 8 + hi * 4];
                        #pragma unroll
                        for (int cht = 0; cht < 4; ++cht)
                            #pragma unroll
                            for (int r = 0; r < 16; ++r)
                                acc[qs][cht][r] *= rv[r >> 2][r & 3];
                    }
                    float pv[16];
                    #pragma unroll
                    for (int r = 0; r < 16; ++r) pv[r] = dev_exp2(s[r] - m_run[qs]);
                    float s8[8];
                    #pragma unroll
                    for (int i = 0; i < 8; ++i) s8[i] = pv[i] + pv[i + 8];
                    float s4a = s8[0] + s8[1], s4b = s8[2] + s8[3];
                    float s4c = s8[4] + s8[5], s4d = s8[6] + s8[7];
                    l_run[qs] += (s4a + s4b) + (s4c + s4d);   // per-half; cross at epilogue

                    // P -> A-fragment (T12): swap(a0,a1) fills words 0 and 2
                    #pragma unroll
                    for (int ks = 0; ks < 2; ++ks) {
                        const int o = ks * 8;
                        unsigned a0 = cvtpk(pv[o + 0], pv[o + 1]);
                        unsigned b0 = cvtpk(pv[o + 2], pv[o + 3]);
                        unsigned a1 = cvtpk(pv[o + 4], pv[o + 5]);
                        unsigned b1 = cvtpk(pv[o + 6], pv[o + 7]);
                        asm volatile("v_permlane32_swap_b32 %0, %1" : "+v"(a0), "+v"(a1));
                        asm volatile("v_permlane32_swap_b32 %0, %1" : "+v"(b0), "+v"(b1));
                        pa[qs][ks][0] = a0; pa[qs][ks][1] = b0;
                        pa[qs][ks][2] = a1; pa[qs][ks][3] = b1;
                    }
                }

                // PV: A = P (regs), B = V^T (LDS b128, imm offsets, conflict-free)
                __builtin_amdgcn_s_setprio(1);
                #pragma unroll
                for (int ks = 0; ks < 2; ++ks) {
                    const int ksl = kb * 2 + ks;
                    #pragma unroll
                    for (int cht = 0; cht < 4; ++cht) {
                        bf16x8 vf = *(const bf16x8*)&VtF[iV[b][ksl] + cht * 2048];
                        #pragma unroll
                        for (int qs = 0; qs < 2; ++qs) {
                            union { unsigned u[4]; bf16x8 v; } pb;
                            pb.u[0] = pa[qs][ks][0]; pb.u[1] = pa[qs][ks][1];
                            pb.u[2] = pa[qs][ks][2]; pb.u[3] = pa[qs][ks][3];
                            acc[qs][cht] = __builtin_amdgcn_mfma_f32_32x32x16_bf16(
                                pb.v, vf, acc[qs][cht], 0, 0, 0);
                        }
                    }
                }
                __builtin_amdgcn_s_setprio(0);
            }
        }
    }

    // epilogue: unnormalized partial O (bf16) + m,l
    const int split = blockIdx.y;
    #pragma unroll
    for (int qs = 0; qs < 2; ++qs) {
        #pragma unroll
        for (int cht = 0; cht < 4; ++cht) {
            int ch = cg * 128 + cht * 32 + l31;
            #pragma unroll
            for (int r = 0; r < 16; ++r) {
                int qq = q0 + qg * 64 + qs * 32 + (r & 3) + 8 * (r >> 2) + 4 * hi;
                po[((size_t)split * N_TOK + qq) * 256 + ch] = f2b(acc[qs][cht][r]);
            }
        }
        float lfull = cross_sum(l_run[qs]);
        if (hi == 0 && cg == 0) {
            int qq = q0 + qg * 64 + qs * 32 + l31;
            pm[(size_t)split * N_TOK + qq] = m_run[qs];
            pl[(size_t)split * N_TOK + qq] = lfull;
        }
    }
}

// ---------------------------------------------------------------------------
// Kernel 4: combine split partials; out = gamma*(O/l) + x
// ---------------------------------------------------------------------------
__global__ __launch_bounds__(256) void combine_kernel(
    const u16* __restrict__ po, const float* __restrict__ pm, const float* __restrict__ pl,
    const float* __restrict__ x, const float* __restrict__ gamma, float* __restrict__ out,
    int nsplit)
{
    const int t = threadIdx.x;
    const int q = blockIdx.x * 4 + (t >> 6);
    const int c4 = (t & 63) * 4;

    float M = -1e30f;
    for (int s = 0; s < nsplit; ++s) M = fmaxf(M, pm[(size_t)s * N_TOK + q]);
    float lsum = 0.f, o0 = 0.f, o1 = 0.f, o2 = 0.f, o3 = 0.f;
    for (int s = 0; s < nsplit; ++s) {
        float wsc = dev_exp2(pm[(size_t)s * N_TOK + q] - M);
        lsum += wsc * pl[(size_t)s * N_TOK + q];
        ushort4 p4 = *(const ushort4*)(po + ((size_t)s * N_TOK + q) * 256 + c4);
        o0 += wsc * b2f(p4.x); o1 += wsc * b2f(p4.y);
        o2 += wsc * b2f(p4.z); o3 += wsc * b2f(p4.w);
    }
    float inv = 1.f / lsum;
    float4 gm = *(const float4*)(gamma + c4);
    float4 xv = *(const float4*)(x + (size_t)q * 256 + c4);
    float4 ov;
    ov.x = gm.x * (o0 * inv) + xv.x;
    ov.y = gm.y * (o1 * inv) + xv.y;
    ov.z = gm.z * (o2 * inv) + xv.z;
    ov.w = gm.w * (o3 * inv) + xv.w;
    *(float4*)(out + (size_t)q * 256 + c4) = ov;
}

// ---------------------------------------------------------------------------
extern "C" void kernel_launch(void* const* d_in, const int* in_sizes, int n_in,
                              void* d_out, int out_size, void* d_ws, size_t ws_size,
                              hipStream_t stream) {
    const float* x     = (const float*)d_in[0];
    const float* wg    = (const float*)d_in[1];
    const float* bg    = (const float*)d_in[2];
    const float* wf    = (const float*)d_in[3];
    const float* bfv   = (const float*)d_in[4];
    const float* wh    = (const float*)d_in[5];
    const float* bh    = (const float*)d_in[6];
    const float* gamma = (const float*)d_in[7];
    float* out = (float*)d_out;

    // split count: need even ntiles (2x-unrolled loop), kps % 64 == 0
    const size_t base_b = (size_t)N_TOK * 640;
    auto need = [&](int ns) {
        return base_b + (size_t)ns * N_TOK * 512 + (size_t)ns * N_TOK * 8 + 1024;
    };
    int nsplit = 4;                                  // 54 tiles
    if (ws_size >= need(9)) nsplit = 9;              // 24 tiles
    else if (ws_size >= need(6)) nsplit = 6;         // 36 tiles
    const int kps = N_TOK / nsplit, ntiles = kps / KT;

    u16* ws = (u16*)d_ws;
    u16* gq = ws;                                   // N*32
    u16* fk = gq + (size_t)N_TOK * 32;              // N*32
    u16* ht = fk + (size_t)N_TOK * 32;              // N*256
    u16* po = ht + (size_t)N_TOK * 256;             // nsplit*N*256 (overlays scratch)
    u16* xb = po;                                   // scratch: N*256
    u16* wt = xb + (size_t)N_TOK * 256;             // 320*256
    u16* hv = wt + 320 * 256;                       // N*256
    float* pm = (float*)(po + (size_t)nsplit * N_TOK * 256);
    float* pl = pm + (size_t)nsplit * N_TOK;

    prep_kernel<<<1728, 512, 0, stream>>>(x, wh, wg, wf, xb, wt);
    proj_kernel<<<dim3(216, 5), 256, 0, stream>>>(xb, wt, bg, bfv, bh, gq, fk, hv);
    transpose_kernel<<<dim3(216, 4), 256, 0, stream>>>(hv, ht);
    attn_kernel<<<dim3(108, nsplit), 256, 0, stream>>>(gq, fk, ht, po, pm, pl, kps, ntiles);
    combine_kernel<<<N_TOK / 4, 256, 0, stream>>>(po, pm, pl, x, gamma, out, nsplit);
}

// Round 7
// 169.692 us; speedup vs baseline: 2.2356x; 1.1466x over previous
//
#include <hip/hip_runtime.h>
#include <math.h>

#define N_TOK 13824
#define KT 32
#define LOG2E 1.44269504088896f

typedef __attribute__((ext_vector_type(8)))  short bf16x8;
typedef __attribute__((ext_vector_type(4)))  float f32x4;
typedef __attribute__((ext_vector_type(16))) float f32x16;
typedef unsigned short u16;

#define AS3(p) ((__attribute__((address_space(3))) void*)(p))
#define AS1(p) ((const __attribute__((address_space(1))) void*)(p))
#define GLL(gp, lp) __builtin_amdgcn_global_load_lds(AS1(gp), AS3(lp), 16, 0, 0)

__device__ inline u16 f2b(float v) {
    union { float f; unsigned u; } a; a.f = v;
    unsigned r = a.u + 0x7fffu + ((a.u >> 16) & 1u);
    return (u16)(r >> 16);
}
__device__ inline float b2f(u16 v) {
    union { unsigned u; float f; } a; a.u = ((unsigned)v) << 16; return a.f;
}
__device__ inline float dev_exp2(float x) {
    float r;
    asm volatile("v_exp_f32 %0, %1" : "=v"(r) : "v"(x));
    return r;
}
// v_permlane32_swap_b32 d, s : d lanes32-63 <-> s lanes0-31
__device__ inline float cross_max(float v) {
    float a = v, b = v;
    asm volatile("v_permlane32_swap_b32 %0, %1" : "+v"(a), "+v"(b));
    return fmaxf(a, b);
}
__device__ inline float cross_sum(float v) {
    float a = v, b = v;
    asm volatile("v_permlane32_swap_b32 %0, %1" : "+v"(a), "+v"(b));
    return a + b;
}
__device__ inline unsigned cvtpk(float lo, float hi) {
    unsigned r;
    asm volatile("v_cvt_pk_bf16_f32 %0, %1, %2" : "=v"(r) : "v"(lo), "v"(hi));
    return r;
}

// ---------------------------------------------------------------------------
// Kernel 0: x -> bf16; weights -> WcatT [320 n][256 k] bf16.
// g-columns (n in [256,288)) pre-scaled by log2e for log2-domain softmax.
// ---------------------------------------------------------------------------
__global__ __launch_bounds__(512) void prep_kernel(
    const float* __restrict__ x, const float* __restrict__ wh,
    const float* __restrict__ wg, const float* __restrict__ wf,
    u16* __restrict__ xb, u16* __restrict__ wt)
{
    int id = blockIdx.x * 512 + threadIdx.x;
    if (id < N_TOK * 256 / 4) {
        float4 v = ((const float4*)x)[id];
        ushort4 o;
        o.x = f2b(v.x); o.y = f2b(v.y); o.z = f2b(v.z); o.w = f2b(v.w);
        ((ushort4*)xb)[id] = o;
    }
    if (id < 320 * 256) {
        int n = id >> 8, k = id & 255;
        float v = (n < 256) ? wh[k * 256 + n]
                : (n < 288) ? wg[k * 32 + (n - 256)] * LOG2E
                            : wf[k * 32 + (n - 288)];
        wt[n * 256 + k] = f2b(v);
    }
}

// ---------------------------------------------------------------------------
// Kernel 1: proj GEMM  [13824,256] x [256,320] -> g[.,32] f[.,32] h[.,256]
// ---------------------------------------------------------------------------
__global__ __launch_bounds__(256) void proj_kernel(
    const u16* __restrict__ xb, const u16* __restrict__ wt,
    const float* __restrict__ bg, const float* __restrict__ bfv, const float* __restrict__ bh,
    u16* __restrict__ g, u16* __restrict__ f, u16* __restrict__ h)
{
    __shared__ u16 As[64 * 64];
    __shared__ u16 Bs[64 * 64];
    const int t = threadIdx.x, l = t & 63, w = t >> 6;
    const int m0 = blockIdx.x * 64, n0 = blockIdx.y * 64;
    const int mh = (w & 1) * 32, nh = (w >> 1) * 32;
    f32x4 acc[2][2] = {};

    for (int kstep = 0; kstep < 4; ++kstep) {
        const int k0 = kstep * 64;
        __syncthreads();
        #pragma unroll
        for (int i = 0; i < 2; ++i) {
            int ch  = w * 2 + i;
            int row = ch * 8 + (l >> 3);
            int ul  = (l & 7) ^ ((l >> 3) & 7);
            GLL(xb + (size_t)(m0 + row) * 256 + k0 + ul * 8, As + ch * 512);
            GLL(wt + (size_t)(n0 + row) * 256 + k0 + ul * 8, Bs + ch * 512);
        }
        asm volatile("s_waitcnt vmcnt(0)" ::: "memory");
        __syncthreads();
        #pragma unroll
        for (int ks = 0; ks < 2; ++ks) {
            bf16x8 a[2], b[2];
            #pragma unroll
            for (int mf = 0; mf < 2; ++mf) {
                int row = mh + mf * 16 + (l & 15);
                int u   = (ks * 4 + (l >> 4)) ^ (row & 7);
                a[mf] = *(const bf16x8*)(As + row * 64 + u * 8);
            }
            #pragma unroll
            for (int nf = 0; nf < 2; ++nf) {
                int row = nh + nf * 16 + (l & 15);
                int u   = (ks * 4 + (l >> 4)) ^ (row & 7);
                b[nf] = *(const bf16x8*)(Bs + row * 64 + u * 8);
            }
            #pragma unroll
            for (int mf = 0; mf < 2; ++mf)
                #pragma unroll
                for (int nf = 0; nf < 2; ++nf)
                    acc[mf][nf] = __builtin_amdgcn_mfma_f32_16x16x32_bf16(
                        a[mf], b[nf], acc[mf][nf], 0, 0, 0);
        }
    }

    #pragma unroll
    for (int mf = 0; mf < 2; ++mf)
        #pragma unroll
        for (int nf = 0; nf < 2; ++nf)
            #pragma unroll
            for (int r = 0; r < 4; ++r) {
                int row = m0 + mh + mf * 16 + (l >> 4) * 4 + r;
                int col = n0 + nh + nf * 16 + (l & 15);
                float bias = (col < 256) ? bh[col]
                           : (col < 288) ? bg[col - 256] * LOG2E
                                         : bfv[col - 288];
                u16 v = f2b(acc[mf][nf][r] + bias);
                if (col < 256)      h[(size_t)row * 256 + col] = v;
                else if (col < 288) g[(size_t)row * 32 + (col - 256)] = v;
                else                f[(size_t)row * 32 + (col - 288)] = v;
            }
}

// ---------------------------------------------------------------------------
// Kernel 2: transpose h [N,256] -> ht [256,N]
// ---------------------------------------------------------------------------
__global__ __launch_bounds__(256) void transpose_kernel(
    const u16* __restrict__ h, u16* __restrict__ ht)
{
    __shared__ u16 tile[64][65];
    const int t = threadIdx.x;
    const int r0 = blockIdx.x * 64, c0 = blockIdx.y * 64;
    #pragma unroll
    for (int i = 0; i < 16; ++i) {
        int r = i * 4 + (t >> 6), c = t & 63;
        tile[r][c] = h[(size_t)(r0 + r) * 256 + c0 + c];
    }
    __syncthreads();
    #pragma unroll
    for (int i = 0; i < 16; ++i) {
        int c = i * 4 + (t >> 6), r = t & 63;
        ht[(size_t)(c0 + c) * N_TOK + r0 + r] = tile[r][c];
    }
}

// ---------------------------------------------------------------------------
// Kernel 3: flash attention. Wave = 32q x 256ch (redundancy-1 softmax).
// Block = 4 waves = 128 q (w = q-group). KT=32 dbuf.
// Swizzle (conflict-free b128): unit p = row*4 + (kg ^ ((row>>1)&3)).
// ---------------------------------------------------------------------------
__global__ __launch_bounds__(256, 2) void attn_kernel(
    const u16* __restrict__ g, const u16* __restrict__ f, const u16* __restrict__ ht,
    u16* __restrict__ po, float* __restrict__ pm, float* __restrict__ pl,
    int kps, int ntiles)
{
    __shared__ u16 VtF[2 * 8192];      // 2 x 16KB V^T tile [256ch][32k]
    __shared__ u16 KsF[2 * 1024];      // 2 x 2KB  K tile   [32k][32c]
    __shared__ float rfs[4][32];

    const int t = threadIdx.x, l = t & 63, w = t >> 6;
    const int hi = l >> 5, l31 = l & 31;
    const int q0 = blockIdx.x * 128 + w * 32;
    const int kbase = blockIdx.y * kps;

    // Q fragments (one 32-q group): B[k][q], col q = l31, k = ks*16 + hi*8 + e
    bf16x8 qf[2];
    #pragma unroll
    for (int ks = 0; ks < 2; ++ks)
        qf[ks] = *(const bf16x8*)(g + (size_t)(q0 + l31) * 32 + ks * 16 + hi * 8);

    f32x16 acc[8] = {};
    float m_run = -1e30f, l_run = 0.f;

    // ---- staging offsets (per-lane, element units) ----
    int voffV[4];
    #pragma unroll
    for (int i = 0; i < 4; ++i) {
        int u = i * 256 + t;
        int ch = u >> 2, gg = u & 3, kg = gg ^ ((ch >> 1) & 3);
        voffV[i] = ch * N_TOK + kg * 8;
    }
    int koffK = 0;
    { int key = (t & 127) >> 2, gcu = t & 3, cu = gcu ^ ((key >> 1) & 3);
      koffK = key * 32 + cu * 8; }

    // ---- compute-read bases (swizzle folded); same formula for V and K ----
    const int sw = (l31 >> 1) & 3;
    int rbase[2];
    #pragma unroll
    for (int ks = 0; ks < 2; ++ks)
        rbase[ks] = (l31 * 4 + ((2 * ks + hi) ^ sw)) * 8;

    auto stage = [&](int tile, int db) {
        const u16* vsrc = ht + kbase + tile * KT;
        #pragma unroll
        for (int i = 0; i < 4; ++i)
            GLL(vsrc + voffV[i], &VtF[db * 8192 + (i * 256 + t) * 8]);
        if (t < 128)
            GLL(f + (size_t)(kbase + tile * KT) * 32 + koffK, &KsF[db * 1024 + t * 8]);
    };

    stage(0, 0);

    for (int tl = 0; tl < ntiles; tl += 2) {
        #pragma unroll
        for (int sub = 0; sub < 2; ++sub) {
            const int b = sub, cur = tl + sub;
            asm volatile("" ::: "memory");
            __builtin_amdgcn_s_barrier();            // all done reading buf b^1
            asm volatile("" ::: "memory");
            { int nx = cur + 1 < ntiles ? cur + 1 : 0; stage(nx, b ^ 1); }
            if (w < 2) asm volatile("s_waitcnt vmcnt(5)" ::: "memory");
            else       asm volatile("s_waitcnt vmcnt(4)" ::: "memory");
            __builtin_amdgcn_s_barrier();            // tile cur staged
            asm volatile("" ::: "memory");

            // K fragments: A[key][c], row key = l31, c = ks*16 + hi*8 + e
            bf16x8 kf0 = *(const bf16x8*)&KsF[b * 1024 + rbase[0]];
            bf16x8 kf1 = *(const bf16x8*)&KsF[b * 1024 + rbase[1]];

            // S = K Q^T : D[key][q], col q = l31, row key = (r&3)+8*(r>>2)+4*hi
            f32x16 z = {};
            z = __builtin_amdgcn_mfma_f32_32x32x16_bf16(kf0, qf[0], z, 0, 0, 0);
            f32x16 s = __builtin_amdgcn_mfma_f32_32x32x16_bf16(kf1, qf[1], z, 0, 0, 0);

            // ---- softmax (once per wave; log2 domain) ----
            float m1 = fmaxf(fmaxf(s[0], s[1]), s[2]);
            float m2 = fmaxf(fmaxf(s[3], s[4]), s[5]);
            float m3 = fmaxf(fmaxf(s[6], s[7]), s[8]);
            float m4 = fmaxf(fmaxf(s[9], s[10]), s[11]);
            float m5 = fmaxf(fmaxf(s[12], s[13]), s[14]);
            float mA = fmaxf(fmaxf(m1, m2), m3);
            float mB = fmaxf(fmaxf(m4, m5), s[15]);
            float mrow = cross_max(fmaxf(mA, mB));

            if (!__all(mrow <= m_run + 11.54f)) {    // defer-max (log2 units)
                float mnew = fmaxf(m_run, mrow);
                float rf = dev_exp2(m_run - mnew);
                m_run = mnew;
                l_run *= rf;
                if (hi == 0) rfs[w][l31] = rf;
                asm volatile("s_waitcnt lgkmcnt(0)" ::: "memory");
                __builtin_amdgcn_sched_barrier(0);
                float4 rv[4];
                #pragma unroll
                for (int bb = 0; bb < 4; ++bb)
                    rv[bb] = *(const float4*)&rfs[w][bb * 8 + hi * 4];
                #pragma unroll
                for (int cht = 0; cht < 8; ++cht)
                    #pragma unroll
                    for (int r = 0; r < 16; ++r)
                        acc[cht][r] *= rv[r >> 2][r & 3];
            }
            float pv[16];
            #pragma unroll
            for (int r = 0; r < 16; ++r) pv[r] = dev_exp2(s[r] - m_run);
            float s8[8];
            #pragma unroll
            for (int i = 0; i < 8; ++i) s8[i] = pv[i] + pv[i + 8];
            float s4a = s8[0] + s8[1], s4b = s8[2] + s8[3];
            float s4c = s8[4] + s8[5], s4d = s8[6] + s8[7];
            l_run += (s4a + s4b) + (s4c + s4d);      // per-half; cross at epilogue

            // P -> A-fragment (T12): swap(a0,a1) fills words 0 and 2
            unsigned pa[2][4];
            #pragma unroll
            for (int ks = 0; ks < 2; ++ks) {
                const int o = ks * 8;
                unsigned a0 = cvtpk(pv[o + 0], pv[o + 1]);
                unsigned b0 = cvtpk(pv[o + 2], pv[o + 3]);
                unsigned a1 = cvtpk(pv[o + 4], pv[o + 5]);
                unsigned b1 = cvtpk(pv[o + 6], pv[o + 7]);
                asm volatile("v_permlane32_swap_b32 %0, %1" : "+v"(a0), "+v"(a1));
                asm volatile("v_permlane32_swap_b32 %0, %1" : "+v"(b0), "+v"(b1));
                pa[ks][0] = a0; pa[ks][1] = b0;
                pa[ks][2] = a1; pa[ks][3] = b1;
            }

            // ---- PV: A = P (regs), B = V^T (LDS b128, conflict-free) ----
            __builtin_amdgcn_s_setprio(1);
            #pragma unroll
            for (int ks = 0; ks < 2; ++ks) {
                union { unsigned u[4]; bf16x8 v; } pb;
                pb.u[0] = pa[ks][0]; pb.u[1] = pa[ks][1];
                pb.u[2] = pa[ks][2]; pb.u[3] = pa[ks][3];
                #pragma unroll
                for (int cht = 0; cht < 8; ++cht) {
                    bf16x8 vf = *(const bf16x8*)&VtF[b * 8192 + cht * 1024 + rbase[ks]];
                    acc[cht] = __builtin_amdgcn_mfma_f32_32x32x16_bf16(
                        pb.v, vf, acc[cht], 0, 0, 0);
                }
            }
            __builtin_amdgcn_s_setprio(0);
        }
    }

    // ---- epilogue: unnormalized partial O (bf16) + m,l ----
    const int split = blockIdx.y;
    #pragma unroll
    for (int cht = 0; cht < 8; ++cht) {
        int ch = cht * 32 + l31;
        #pragma unroll
        for (int r = 0; r < 16; ++r) {
            int qq = q0 + (r & 3) + 8 * (r >> 2) + 4 * hi;
            po[((size_t)split * N_TOK + qq) * 256 + ch] = f2b(acc[cht][r]);
        }
    }
    float lfull = cross_sum(l_run);
    if (hi == 0) {
        int qq = q0 + l31;
        pm[(size_t)split * N_TOK + qq] = m_run;
        pl[(size_t)split * N_TOK + qq] = lfull;
    }
}

// ---------------------------------------------------------------------------
// Kernel 4: combine split partials; out = gamma*(O/l) + x
// ---------------------------------------------------------------------------
__global__ __launch_bounds__(256) void combine_kernel(
    const u16* __restrict__ po, const float* __restrict__ pm, const float* __restrict__ pl,
    const float* __restrict__ x, const float* __restrict__ gamma, float* __restrict__ out,
    int nsplit)
{
    const int t = threadIdx.x;
    const int q = blockIdx.x * 4 + (t >> 6);
    const int c4 = (t & 63) * 4;

    float M = -1e30f;
    for (int s = 0; s < nsplit; ++s) M = fmaxf(M, pm[(size_t)s * N_TOK + q]);
    float lsum = 0.f, o0 = 0.f, o1 = 0.f, o2 = 0.f, o3 = 0.f;
    for (int s = 0; s < nsplit; ++s) {
        float wsc = dev_exp2(pm[(size_t)s * N_TOK + q] - M);
        lsum += wsc * pl[(size_t)s * N_TOK + q];
        ushort4 p4 = *(const ushort4*)(po + ((size_t)s * N_TOK + q) * 256 + c4);
        o0 += wsc * b2f(p4.x); o1 += wsc * b2f(p4.y);
        o2 += wsc * b2f(p4.z); o3 += wsc * b2f(p4.w);
    }
    float inv = 1.f / lsum;
    float4 gm = *(const float4*)(gamma + c4);
    float4 xv = *(const float4*)(x + (size_t)q * 256 + c4);
    float4 ov;
    ov.x = gm.x * (o0 * inv) + xv.x;
    ov.y = gm.y * (o1 * inv) + xv.y;
    ov.z = gm.z * (o2 * inv) + xv.z;
    ov.w = gm.w * (o3 * inv) + xv.w;
    *(float4*)(out + (size_t)q * 256 + c4) = ov;
}

// ---------------------------------------------------------------------------
extern "C" void kernel_launch(void* const* d_in, const int* in_sizes, int n_in,
                              void* d_out, int out_size, void* d_ws, size_t ws_size,
                              hipStream_t stream) {
    const float* x     = (const float*)d_in[0];
    const float* wg    = (const float*)d_in[1];
    const float* bg    = (const float*)d_in[2];
    const float* wf    = (const float*)d_in[3];
    const float* bfv   = (const float*)d_in[4];
    const float* wh    = (const float*)d_in[5];
    const float* bh    = (const float*)d_in[6];
    const float* gamma = (const float*)d_in[7];
    float* out = (float*)d_out;

    const size_t base_b = (size_t)N_TOK * 640;
    auto need = [&](int ns) {
        return base_b + (size_t)ns * N_TOK * 512 + (size_t)ns * N_TOK * 8 + 1024;
    };
    int nsplit = 4;
    if (ws_size >= need(9)) nsplit = 9;
    else if (ws_size >= need(6)) nsplit = 6;
    const int kps = N_TOK / nsplit, ntiles = kps / KT;   // 48 / 72 / 108, all even

    u16* ws = (u16*)d_ws;
    u16* gq = ws;                                   // N*32
    u16* fk = gq + (size_t)N_TOK * 32;              // N*32
    u16* ht = fk + (size_t)N_TOK * 32;              // N*256
    u16* po = ht + (size_t)N_TOK * 256;             // nsplit*N*256 (overlays scratch)
    u16* xb = po;                                   // scratch: N*256
    u16* wt = xb + (size_t)N_TOK * 256;             // 320*256
    u16* hv = wt + 320 * 256;                       // N*256
    float* pm = (float*)(po + (size_t)nsplit * N_TOK * 256);
    float* pl = pm + (size_t)nsplit * N_TOK;

    prep_kernel<<<1728, 512, 0, stream>>>(x, wh, wg, wf, xb, wt);
    proj_kernel<<<dim3(216, 5), 256, 0, stream>>>(xb, wt, bg, bfv, bh, gq, fk, hv);
    transpose_kernel<<<dim3(216, 4), 256, 0, stream>>>(hv, ht);
    attn_kernel<<<dim3(108, nsplit), 256, 0, stream>>>(gq, fk, ht, po, pm, pl, kps, ntiles);
    combine_kernel<<<N_TOK / 4, 256, 0, stream>>>(po, pm, pl, x, gamma, out, nsplit);
}

// Round 8
// 169.683 us; speedup vs baseline: 2.2358x; 1.0001x over previous
//
#include <hip/hip_runtime.h>
#include <math.h>

#define N_TOK 13824
#define KT 32
#define LOG2E 1.44269504088896f

typedef __attribute__((ext_vector_type(8)))  short bf16x8;
typedef __attribute__((ext_vector_type(4)))  float f32x4;
typedef __attribute__((ext_vector_type(16))) float f32x16;
typedef unsigned short u16;

#define AS3(p) ((__attribute__((address_space(3))) void*)(p))
#define AS1(p) ((const __attribute__((address_space(1))) void*)(p))
#define GLL(gp, lp) __builtin_amdgcn_global_load_lds(AS1(gp), AS3(lp), 16, 0, 0)

__device__ inline u16 f2b(float v) {
    union { float f; unsigned u; } a; a.f = v;
    unsigned r = a.u + 0x7fffu + ((a.u >> 16) & 1u);
    return (u16)(r >> 16);
}
__device__ inline float b2f(u16 v) {
    union { unsigned u; float f; } a; a.u = ((unsigned)v) << 16; return a.f;
}
__device__ inline float dev_exp2(float x) {
    float r;
    asm volatile("v_exp_f32 %0, %1" : "=v"(r) : "v"(x));
    return r;
}
// v_permlane32_swap_b32 d, s : d lanes32-63 <-> s lanes0-31
__device__ inline float cross_max(float v) {
    float a = v, b = v;
    asm volatile("v_permlane32_swap_b32 %0, %1" : "+v"(a), "+v"(b));
    return fmaxf(a, b);
}
__device__ inline float cross_sum(float v) {
    float a = v, b = v;
    asm volatile("v_permlane32_swap_b32 %0, %1" : "+v"(a), "+v"(b));
    return a + b;
}
__device__ inline unsigned cvtpk(float lo, float hi) {
    unsigned r;
    asm volatile("v_cvt_pk_bf16_f32 %0, %1, %2" : "=v"(r) : "v"(lo), "v"(hi));
    return r;
}

// ---------------------------------------------------------------------------
// Kernel 0: x -> bf16; weights -> WcatT [320 n][256 k] bf16.
// g-columns (n in [256,288)) pre-scaled by log2e for log2-domain softmax.
// ---------------------------------------------------------------------------
__global__ __launch_bounds__(512) void prep_kernel(
    const float* __restrict__ x, const float* __restrict__ wh,
    const float* __restrict__ wg, const float* __restrict__ wf,
    u16* __restrict__ xb, u16* __restrict__ wt)
{
    int id = blockIdx.x * 512 + threadIdx.x;
    if (id < N_TOK * 256 / 4) {
        float4 v = ((const float4*)x)[id];
        ushort4 o;
        o.x = f2b(v.x); o.y = f2b(v.y); o.z = f2b(v.z); o.w = f2b(v.w);
        ((ushort4*)xb)[id] = o;
    }
    if (id < 320 * 256) {
        int n = id >> 8, k = id & 255;
        float v = (n < 256) ? wh[k * 256 + n]
                : (n < 288) ? wg[k * 32 + (n - 256)] * LOG2E
                            : wf[k * 32 + (n - 288)];
        wt[n * 256 + k] = f2b(v);
    }
}

// ---------------------------------------------------------------------------
// Kernel 1: proj GEMM  [13824,256] x [256,320] -> g[.,32] f[.,32] h[.,256]
// ---------------------------------------------------------------------------
__global__ __launch_bounds__(256) void proj_kernel(
    const u16* __restrict__ xb, const u16* __restrict__ wt,
    const float* __restrict__ bg, const float* __restrict__ bfv, const float* __restrict__ bh,
    u16* __restrict__ g, u16* __restrict__ f, u16* __restrict__ h)
{
    __shared__ u16 As[64 * 64];
    __shared__ u16 Bs[64 * 64];
    const int t = threadIdx.x, l = t & 63, w = t >> 6;
    const int m0 = blockIdx.x * 64, n0 = blockIdx.y * 64;
    const int mh = (w & 1) * 32, nh = (w >> 1) * 32;
    f32x4 acc[2][2] = {};

    for (int kstep = 0; kstep < 4; ++kstep) {
        const int k0 = kstep * 64;
        __syncthreads();
        #pragma unroll
        for (int i = 0; i < 2; ++i) {
            int ch  = w * 2 + i;
            int row = ch * 8 + (l >> 3);
            int ul  = (l & 7) ^ ((l >> 3) & 7);
            GLL(xb + (size_t)(m0 + row) * 256 + k0 + ul * 8, As + ch * 512);
            GLL(wt + (size_t)(n0 + row) * 256 + k0 + ul * 8, Bs + ch * 512);
        }
        asm volatile("s_waitcnt vmcnt(0)" ::: "memory");
        __syncthreads();
        #pragma unroll
        for (int ks = 0; ks < 2; ++ks) {
            bf16x8 a[2], b[2];
            #pragma unroll
            for (int mf = 0; mf < 2; ++mf) {
                int row = mh + mf * 16 + (l & 15);
                int u   = (ks * 4 + (l >> 4)) ^ (row & 7);
                a[mf] = *(const bf16x8*)(As + row * 64 + u * 8);
            }
            #pragma unroll
            for (int nf = 0; nf < 2; ++nf) {
                int row = nh + nf * 16 + (l & 15);
                int u   = (ks * 4 + (l >> 4)) ^ (row & 7);
                b[nf] = *(const bf16x8*)(Bs + row * 64 + u * 8);
            }
            #pragma unroll
            for (int mf = 0; mf < 2; ++mf)
                #pragma unroll
                for (int nf = 0; nf < 2; ++nf)
                    acc[mf][nf] = __builtin_amdgcn_mfma_f32_16x16x32_bf16(
                        a[mf], b[nf], acc[mf][nf], 0, 0, 0);
        }
    }

    #pragma unroll
    for (int mf = 0; mf < 2; ++mf)
        #pragma unroll
        for (int nf = 0; nf < 2; ++nf)
            #pragma unroll
            for (int r = 0; r < 4; ++r) {
                int row = m0 + mh + mf * 16 + (l >> 4) * 4 + r;
                int col = n0 + nh + nf * 16 + (l & 15);
                float bias = (col < 256) ? bh[col]
                           : (col < 288) ? bg[col - 256] * LOG2E
                                         : bfv[col - 288];
                u16 v = f2b(acc[mf][nf][r] + bias);
                if (col < 256)      h[(size_t)row * 256 + col] = v;
                else if (col < 288) g[(size_t)row * 32 + (col - 256)] = v;
                else                f[(size_t)row * 32 + (col - 288)] = v;
            }
}

// ---------------------------------------------------------------------------
// Kernel 2: transpose h [N,256] -> ht [256,N]
// ---------------------------------------------------------------------------
__global__ __launch_bounds__(256) void transpose_kernel(
    const u16* __restrict__ h, u16* __restrict__ ht)
{
    __shared__ u16 tile[64][65];
    const int t = threadIdx.x;
    const int r0 = blockIdx.x * 64, c0 = blockIdx.y * 64;
    #pragma unroll
    for (int i = 0; i < 16; ++i) {
        int r = i * 4 + (t >> 6), c = t & 63;
        tile[r][c] = h[(size_t)(r0 + r) * 256 + c0 + c];
    }
    __syncthreads();
    #pragma unroll
    for (int i = 0; i < 16; ++i) {
        int c = i * 4 + (t >> 6), r = t & 63;
        ht[(size_t)(c0 + c) * N_TOK + r0 + r] = tile[r][c];
    }
}

// ---------------------------------------------------------------------------
// Kernel 3: flash attention. Wave = 32q x 256ch (redundancy-1 softmax).
// Block = 4 waves = 128 q (w = q-group). KT=32 dbuf.
// Swizzle (conflict-free b128): unit p = row*4 + (kg ^ ((row>>1)&3)).
// ---------------------------------------------------------------------------
__global__ __launch_bounds__(256, 2) void attn_kernel(
    const u16* __restrict__ g, const u16* __restrict__ f, const u16* __restrict__ ht,
    u16* __restrict__ po, float* __restrict__ pm, float* __restrict__ pl,
    int kps, int ntiles)
{
    __shared__ u16 VtF[2 * 8192];      // 2 x 16KB V^T tile [256ch][32k]
    __shared__ u16 KsF[2 * 1024];      // 2 x 2KB  K tile   [32k][32c]
    __shared__ float rfs[4][32];

    const int t = threadIdx.x, l = t & 63, w = t >> 6;
    const int hi = l >> 5, l31 = l & 31;
    const int q0 = blockIdx.x * 128 + w * 32;
    const int kbase = blockIdx.y * kps;

    // Q fragments (one 32-q group): B[k][q], col q = l31, k = ks*16 + hi*8 + e
    bf16x8 qf[2];
    #pragma unroll
    for (int ks = 0; ks < 2; ++ks)
        qf[ks] = *(const bf16x8*)(g + (size_t)(q0 + l31) * 32 + ks * 16 + hi * 8);

    f32x16 acc[8] = {};
    float m_run = -1e30f, l_run = 0.f;

    // ---- staging offsets (per-lane, element units) ----
    int voffV[4];
    #pragma unroll
    for (int i = 0; i < 4; ++i) {
        int u = i * 256 + t;
        int ch = u >> 2, gg = u & 3, kg = gg ^ ((ch >> 1) & 3);
        voffV[i] = ch * N_TOK + kg * 8;
    }
    int koffK = 0;
    { int key = (t & 127) >> 2, gcu = t & 3, cu = gcu ^ ((key >> 1) & 3);
      koffK = key * 32 + cu * 8; }

    // ---- compute-read bases (swizzle folded); same formula for V and K ----
    const int sw = (l31 >> 1) & 3;
    int rbase[2];
    #pragma unroll
    for (int ks = 0; ks < 2; ++ks)
        rbase[ks] = (l31 * 4 + ((2 * ks + hi) ^ sw)) * 8;

    auto stage = [&](int tile, int db) {
        const u16* vsrc = ht + kbase + tile * KT;
        #pragma unroll
        for (int i = 0; i < 4; ++i)
            GLL(vsrc + voffV[i], &VtF[db * 8192 + (i * 256 + t) * 8]);
        if (t < 128)
            GLL(f + (size_t)(kbase + tile * KT) * 32 + koffK, &KsF[db * 1024 + t * 8]);
    };

    stage(0, 0);

    for (int tl = 0; tl < ntiles; tl += 2) {
        #pragma unroll
        for (int sub = 0; sub < 2; ++sub) {
            const int b = sub, cur = tl + sub;
            asm volatile("" ::: "memory");
            __builtin_amdgcn_s_barrier();            // all done reading buf b^1
            asm volatile("" ::: "memory");
            { int nx = cur + 1 < ntiles ? cur + 1 : 0; stage(nx, b ^ 1); }
            if (w < 2) asm volatile("s_waitcnt vmcnt(5)" ::: "memory");
            else       asm volatile("s_waitcnt vmcnt(4)" ::: "memory");
            __builtin_amdgcn_s_barrier();            // tile cur staged
            asm volatile("" ::: "memory");

            // K fragments: A[key][c], row key = l31, c = ks*16 + hi*8 + e
            bf16x8 kf0 = *(const bf16x8*)&KsF[b * 1024 + rbase[0]];
            bf16x8 kf1 = *(const bf16x8*)&KsF[b * 1024 + rbase[1]];

            // S = K Q^T : D[key][q], col q = l31, row key = (r&3)+8*(r>>2)+4*hi
            f32x16 z = {};
            z = __builtin_amdgcn_mfma_f32_32x32x16_bf16(kf0, qf[0], z, 0, 0, 0);
            f32x16 s = __builtin_amdgcn_mfma_f32_32x32x16_bf16(kf1, qf[1], z, 0, 0, 0);

            // ---- softmax (once per wave; log2 domain) ----
            float m1 = fmaxf(fmaxf(s[0], s[1]), s[2]);
            float m2 = fmaxf(fmaxf(s[3], s[4]), s[5]);
            float m3 = fmaxf(fmaxf(s[6], s[7]), s[8]);
            float m4 = fmaxf(fmaxf(s[9], s[10]), s[11]);
            float m5 = fmaxf(fmaxf(s[12], s[13]), s[14]);
            float mA = fmaxf(fmaxf(m1, m2), m3);
            float mB = fmaxf(fmaxf(m4, m5), s[15]);
            float mrow = cross_max(fmaxf(mA, mB));

            if (!__all(mrow <= m_run + 11.54f)) {    // defer-max (log2 units)
                float mnew = fmaxf(m_run, mrow);
                float rf = dev_exp2(m_run - mnew);
                m_run = mnew;
                l_run *= rf;
                if (hi == 0) rfs[w][l31] = rf;
                asm volatile("s_waitcnt lgkmcnt(0)" ::: "memory");
                __builtin_amdgcn_sched_barrier(0);
                float4 rv[4];
                #pragma unroll
                for (int bb = 0; bb < 4; ++bb)
                    rv[bb] = *(const float4*)&rfs[w][bb * 8 + hi * 4];
                #pragma unroll
                for (int cht = 0; cht < 8; ++cht)
                    #pragma unroll
                    for (int r = 0; r < 16; ++r)
                        acc[cht][r] *= rv[r >> 2][r & 3];
            }
            float pv[16];
            #pragma unroll
            for (int r = 0; r < 16; ++r) pv[r] = dev_exp2(s[r] - m_run);
            float s8[8];
            #pragma unroll
            for (int i = 0; i < 8; ++i) s8[i] = pv[i] + pv[i + 8];
            float s4a = s8[0] + s8[1], s4b = s8[2] + s8[3];
            float s4c = s8[4] + s8[5], s4d = s8[6] + s8[7];
            l_run += (s4a + s4b) + (s4c + s4d);      // per-half; cross at epilogue

            // P -> A-fragment (T12): swap(a0,a1) fills words 0 and 2
            unsigned pa[2][4];
            #pragma unroll
            for (int ks = 0; ks < 2; ++ks) {
                const int o = ks * 8;
                unsigned a0 = cvtpk(pv[o + 0], pv[o + 1]);
                unsigned b0 = cvtpk(pv[o + 2], pv[o + 3]);
                unsigned a1 = cvtpk(pv[o + 4], pv[o + 5]);
                unsigned b1 = cvtpk(pv[o + 6], pv[o + 7]);
                asm volatile("v_permlane32_swap_b32 %0, %1" : "+v"(a0), "+v"(a1));
                asm volatile("v_permlane32_swap_b32 %0, %1" : "+v"(b0), "+v"(b1));
                pa[ks][0] = a0; pa[ks][1] = b0;
                pa[ks][2] = a1; pa[ks][3] = b1;
            }

            // ---- PV: A = P (regs), B = V^T (LDS b128, conflict-free) ----
            __builtin_amdgcn_s_setprio(1);
            #pragma unroll
            for (int ks = 0; ks < 2; ++ks) {
                union { unsigned u[4]; bf16x8 v; } pb;
                pb.u[0] = pa[ks][0]; pb.u[1] = pa[ks][1];
                pb.u[2] = pa[ks][2]; pb.u[3] = pa[ks][3];
                #pragma unroll
                for (int cht = 0; cht < 8; ++cht) {
                    bf16x8 vf = *(const bf16x8*)&VtF[b * 8192 + cht * 1024 + rbase[ks]];
                    acc[cht] = __builtin_amdgcn_mfma_f32_32x32x16_bf16(
                        pb.v, vf, acc[cht], 0, 0, 0);
                }
            }
            __builtin_amdgcn_s_setprio(0);
        }
    }

    // ---- epilogue: unnormalized partial O (bf16) + m,l ----
    const int split = blockIdx.y;
    #pragma unroll
    for (int cht = 0; cht < 8; ++cht) {
        int ch = cht * 32 + l31;
        #pragma unroll
        for (int r = 0; r < 16; ++r) {
            int qq = q0 + (r & 3) + 8 * (r >> 2) + 4 * hi;
            po[((size_t)split * N_TOK + qq) * 256 + ch] = f2b(acc[cht][r]);
        }
    }
    float lfull = cross_sum(l_run);
    if (hi == 0) {
        int qq = q0 + l31;
        pm[(size_t)split * N_TOK + qq] = m_run;
        pl[(size_t)split * N_TOK + qq] = lfull;
    }
}

// ---------------------------------------------------------------------------
// Kernel 4: combine split partials; out = gamma*(O/l) + x
// ---------------------------------------------------------------------------
__global__ __launch_bounds__(256) void combine_kernel(
    const u16* __restrict__ po, const float* __restrict__ pm, const float* __restrict__ pl,
    const float* __restrict__ x, const float* __restrict__ gamma, float* __restrict__ out,
    int nsplit)
{
    const int t = threadIdx.x;
    const int q = blockIdx.x * 4 + (t >> 6);
    const int c4 = (t & 63) * 4;

    float M = -1e30f;
    for (int s = 0; s < nsplit; ++s) M = fmaxf(M, pm[(size_t)s * N_TOK + q]);
    float lsum = 0.f, o0 = 0.f, o1 = 0.f, o2 = 0.f, o3 = 0.f;
    for (int s = 0; s < nsplit; ++s) {
        float wsc = dev_exp2(pm[(size_t)s * N_TOK + q] - M);
        lsum += wsc * pl[(size_t)s * N_TOK + q];
        ushort4 p4 = *(const ushort4*)(po + ((size_t)s * N_TOK + q) * 256 + c4);
        o0 += wsc * b2f(p4.x); o1 += wsc * b2f(p4.y);
        o2 += wsc * b2f(p4.z); o3 += wsc * b2f(p4.w);
    }
    float inv = 1.f / lsum;
    float4 gm = *(const float4*)(gamma + c4);
    float4 xv = *(const float4*)(x + (size_t)q * 256 + c4);
    float4 ov;
    ov.x = gm.x * (o0 * inv) + xv.x;
    ov.y = gm.y * (o1 * inv) + xv.y;
    ov.z = gm.z * (o2 * inv) + xv.z;
    ov.w = gm.w * (o3 * inv) + xv.w;
    *(float4*)(out + (size_t)q * 256 + c4) = ov;
}

// ---------------------------------------------------------------------------
extern "C" void kernel_launch(void* const* d_in, const int* in_sizes, int n_in,
                              void* d_out, int out_size, void* d_ws, size_t ws_size,
                              hipStream_t stream) {
    const float* x     = (const float*)d_in[0];
    const float* wg    = (const float*)d_in[1];
    const float* bg    = (const float*)d_in[2];
    const float* wf    = (const float*)d_in[3];
    const float* bfv   = (const float*)d_in[4];
    const float* wh    = (const float*)d_in[5];
    const float* bh    = (const float*)d_in[6];
    const float* gamma = (const float*)d_in[7];
    float* out = (float*)d_out;

    const size_t base_b = (size_t)N_TOK * 640;
    auto need = [&](int ns) {
        return base_b + (size_t)ns * N_TOK * 512 + (size_t)ns * N_TOK * 8 + 1024;
    };
    int nsplit = 4;
    if (ws_size >= need(9)) nsplit = 9;
    else if (ws_size >= need(6)) nsplit = 6;
    const int kps = N_TOK / nsplit, ntiles = kps / KT;   // 48 / 72 / 108, all even

    u16* ws = (u16*)d_ws;
    u16* gq = ws;                                   // N*32
    u16* fk = gq + (size_t)N_TOK * 32;              // N*32
    u16* ht = fk + (size_t)N_TOK * 32;              // N*256
    u16* po = ht + (size_t)N_TOK * 256;             // nsplit*N*256 (overlays scratch)
    u16* xb = po;                                   // scratch: N*256
    u16* wt = xb + (size_t)N_TOK * 256;             // 320*256
    u16* hv = wt + 320 * 256;                       // N*256
    float* pm = (float*)(po + (size_t)nsplit * N_TOK * 256);
    float* pl = pm + (size_t)nsplit * N_TOK;

    prep_kernel<<<1728, 512, 0, stream>>>(x, wh, wg, wf, xb, wt);
    proj_kernel<<<dim3(216, 5), 256, 0, stream>>>(xb, wt, bg, bfv, bh, gq, fk, hv);
    transpose_kernel<<<dim3(216, 4), 256, 0, stream>>>(hv, ht);
    attn_kernel<<<dim3(108, nsplit), 256, 0, stream>>>(gq, fk, ht, po, pm, pl, kps, ntiles);
    combine_kernel<<<N_TOK / 4, 256, 0, stream>>>(po, pm, pl, x, gamma, out, nsplit);
}